// Round 4
// baseline (184.731 us; speedup 1.0000x reference)
//
#include <hip/hip_runtime.h>

typedef __attribute__((ext_vector_type(8))) short bf16x8;
typedef __attribute__((ext_vector_type(4))) float f32x4;
typedef __attribute__((ext_vector_type(2))) unsigned short u16x2;
typedef __attribute__((ext_vector_type(4))) unsigned short u16x4;

static constexpr int kB = 2;
static constexpr int kT = 2048;
static constexpr int kC = 1024;
static constexpr int kH = 16;
static constexpr int kD = 64;

__device__ inline unsigned short f2bf(float f) {
    unsigned int u = __float_as_uint(f);
    u += 0x7FFFu + ((u >> 16) & 1u);
    return (unsigned short)(u >> 16);
}

#define GLDS16(g, s)                                                            \
    __builtin_amdgcn_global_load_lds(                                           \
        (const __attribute__((address_space(1))) unsigned int*)(g),             \
        (__attribute__((address_space(3))) unsigned int*)(s), 16, 0, 0)

#define WAITVM(N) asm volatile("s_waitcnt vmcnt(" #N ")" ::: "memory")
#define WAITLG() asm volatile("s_waitcnt lgkmcnt(0)" ::: "memory")
#define SCHEDB() __builtin_amdgcn_sched_barrier(0)
#define SBAR() __builtin_amdgcn_s_barrier()

// ---------------- f32 -> bf16 convert ----------------
__global__ __launch_bounds__(256) void cvt_bf16(const float* __restrict__ in,
                                                unsigned short* __restrict__ out, int n) {
    int i = (blockIdx.x * 256 + threadIdx.x) * 4;
    if (i >= n) return;
    float4 v = *(const float4*)(in + i);
    u16x4 o;
    o[0] = f2bf(v.x); o[1] = f2bf(v.y); o[2] = f2bf(v.z); o[3] = f2bf(v.w);
    *(u16x4*)(out + i) = o;
}

// ---------------- RoPE/xPos tables ----------------
__global__ __launch_bounds__(256) void rope_tables(float* __restrict__ ct,
                                                   float* __restrict__ st,
                                                   float* __restrict__ sc) {
    int idx = blockIdx.x * 256 + threadIdx.x;
    if (idx >= kT * 32) return;
    int t = idx >> 5, i = idx & 31;
    float half = 2.0f * (float)i;
    float inv_freq = powf(10000.0f, -half / 64.0f);
    float fr = (float)t * inv_freq;
    float sv = (half + 0.4f * 64.0f) / (1.4f * 64.0f);
    float p = ((float)t - 1024.0f) / 512.0f;
    ct[idx] = cosf(fr);
    st[idx] = sinf(fr);
    sc[idx] = powf(sv, p);
}

// ---------------- bf16 MFMA GEMM: C[M,N] = A[M,K] * Bm[N,K]^T, fp32 out ----------
// tile 128x128, BK=64, 4 waves (2x2). Double-buffered global_load_lds staging with
// counted vmcnt (T3/T4 2-phase pipeline); LDS reads XOR-swizzled, conflict-free.
__global__ __launch_bounds__(256) void gemm128(const unsigned short* __restrict__ A,
                                               const unsigned short* __restrict__ Bm,
                                               float* __restrict__ Cm,
                                               int N, int K) {
    __shared__ unsigned short Al[2][128 * 64];
    __shared__ unsigned short Bl[2][128 * 64];
    const int tid = threadIdx.x;
    const int l = tid & 63, w = tid >> 6;
    const int wr = w >> 1, wc = w & 1;
    const int tm = blockIdx.y * 128, tn = blockIdx.x * 128;
    const int ri = l >> 3;               // row within 8-row chunk
    const int su = (l & 7) ^ (ri & 7);   // pre-swizzled 16B unit within row
    const int NK = K >> 6;

    f32x4 zero4 = {0.0f, 0.0f, 0.0f, 0.0f};
    f32x4 acc[4][4];
#pragma unroll
    for (int m = 0; m < 4; m++)
#pragma unroll
        for (int n = 0; n < 4; n++) acc[m][n] = zero4;

    // stage tile (kt element offset) into buffer pb: 8 GLDS16 per thread
    auto STAGE = [&](int kt, int pb) {
        char* ab = (char*)Al[pb];
        char* bb = (char*)Bl[pb];
#pragma unroll
        for (int c = w; c < 16; c += 4) {
            const unsigned short* src = A + (size_t)(tm + c * 8 + ri) * K + kt + su * 8;
            GLDS16(src, ab + c * 1024);
        }
#pragma unroll
        for (int c = w; c < 16; c += 4) {
            const unsigned short* src = Bm + (size_t)(tn + c * 8 + ri) * K + kt + su * 8;
            GLDS16(src, bb + c * 1024);
        }
    };

    STAGE(0, 0);
    for (int i = 0; i < NK; ++i) {
        const int cur = i & 1;
        if (i + 1 < NK) {
            STAGE((i + 1) * 64, cur ^ 1);
            WAITVM(8);
        } else {
            WAITVM(0);
        }
        SCHEDB();
        SBAR();
        char* ab = (char*)Al[cur];
        char* bb = (char*)Bl[cur];
#pragma unroll
        for (int ks = 0; ks < 2; ks++) {
            bf16x8 af[4], bfr[4];
            int kbyte = ks * 64 + (l >> 4) * 16;
#pragma unroll
            for (int m = 0; m < 4; m++) {
                int row = wr * 64 + m * 16 + (l & 15);
                af[m] = *(const bf16x8*)(ab + row * 128 + (kbyte ^ ((row & 7) << 4)));
            }
#pragma unroll
            for (int n = 0; n < 4; n++) {
                int row = wc * 64 + n * 16 + (l & 15);
                bfr[n] = *(const bf16x8*)(bb + row * 128 + (kbyte ^ ((row & 7) << 4)));
            }
#pragma unroll
            for (int m = 0; m < 4; m++)
#pragma unroll
                for (int n = 0; n < 4; n++)
                    acc[m][n] = __builtin_amdgcn_mfma_f32_16x16x32_bf16(af[m], bfr[n], acc[m][n], 0, 0, 0);
        }
        WAITLG();
        SCHEDB();
        SBAR();
    }
#pragma unroll
    for (int m = 0; m < 4; m++)
#pragma unroll
        for (int n = 0; n < 4; n++)
#pragma unroll
            for (int r = 0; r < 4; r++) {
                int row = tm + wr * 64 + m * 16 + (l >> 4) * 4 + r;
                int col = tn + wc * 64 + n * 16 + (l & 15);
                Cm[(size_t)row * N + col] = acc[m][n][r];
            }
}

// ---------------- RoPE q+k fused, with decay pre-scales folded in -------------
__global__ __launch_bounds__(256) void rope_qk(const float* __restrict__ src,
                                               const float* __restrict__ ct,
                                               const float* __restrict__ st,
                                               const float* __restrict__ sc,
                                               unsigned short* __restrict__ dq,
                                               unsigned short* __restrict__ dk) {
    int idx = blockIdx.x * 256 + threadIdx.x;  // B*T*H*32
    if (idx >= kB * kT * kH * 32) return;
    int i = idx & 31;
    int h = (idx >> 5) & 15;
    int t = (idx >> 9) & 2047;
    int b = idx >> 20;
    size_t row = (size_t)(b * kT + t) * 2048;
    float2 qv = *(const float2*)(src + row + h * kD + 2 * i);
    float2 kv = *(const float2*)(src + row + 1024 + h * kD + 2 * i);
    int ti = t * 32 + i;
    float c = ct[ti], s = st[ti], sv = sc[ti];
    float log2g = log2f(1.0f - exp2f(-5.0f - (float)h));
    float qdec = 0.125f * exp2f(log2g * (float)(t & 127));
    float kdec = exp2f(-log2g * (float)(t & 63));
    float cq = c * sv, sq = s * sv;
    float ck = c / sv, sk = s / sv;
    float q0 = (qv.x * cq - qv.y * sq) * qdec;
    float q1 = (qv.y * cq + qv.x * sq) * qdec;
    float k0 = (kv.x * ck - kv.y * sk) * kdec;
    float k1 = (kv.y * ck + kv.x * sk) * kdec;
    size_t doff = (((size_t)(b * kH + h) * kT + t) * kD) + 2 * i;
    u16x2 oq, ok;
    oq[0] = f2bf(q0); oq[1] = f2bf(q1);
    ok[0] = f2bf(k0); ok[1] = f2bf(k1);
    *(u16x2*)(dq + doff) = oq;
    *(u16x2*)(dk + doff) = ok;
}

// ---------------- V: fp32 (B*T, C) -> bf16 transposed (B,H,D,T) ----------------
__global__ __launch_bounds__(256) void vt_from_f32(const float* __restrict__ vf,
                                                   unsigned short* __restrict__ vtb) {
    __shared__ unsigned short tile[64][72];
    int tt = blockIdx.x * 64;
    int bh = blockIdx.y;
    int b = bh >> 4, h = bh & 15;
    int r = threadIdx.x >> 2;
    int cu = (threadIdx.x & 3) * 16;
    const float* srow = vf + ((size_t)(b * kT) + tt + r) * kC + h * kD + cu;
#pragma unroll
    for (int j = 0; j < 16; j += 4) {
        float4 v = *(const float4*)(srow + j);
        tile[r][cu + j + 0] = f2bf(v.x);
        tile[r][cu + j + 1] = f2bf(v.y);
        tile[r][cu + j + 2] = f2bf(v.z);
        tile[r][cu + j + 3] = f2bf(v.w);
    }
    __syncthreads();
    int d = threadIdx.x >> 2;
    int tb = (threadIdx.x & 3) * 16;
    bf16x8 o0, o1;
#pragma unroll
    for (int e = 0; e < 8; e++) {
        o0[e] = (short)tile[tb + e][d];
        o1[e] = (short)tile[tb + 8 + e][d];
    }
    unsigned short* drow = vtb + ((size_t)bh * kD + d) * kT + tt + tb;
    *(bf16x8*)(drow) = o0;
    *(bf16x8*)(drow + 8) = o1;
}

// ---------------- retention attention ----------------
// grid (32, 8): blockIdx.x = bh (XCD = bh%8 -> per-XCD K/V footprint 2MB, L2-fits),
// blockIdx.y = pair index (q-tiles pair and 15-pair). 512 threads = 8 waves; each
// wave owns 16 q-rows of the 128-row q-tile. Double-buffered K/V staging with
// counted vmcnt pipeline. q pre-scaled by 0.125*g^(t&127), k by g^(-(s&63)).
__global__ __launch_bounds__(512) void retention_attn(const unsigned short* __restrict__ qb,
                                                      const unsigned short* __restrict__ kb,
                                                      const unsigned short* __restrict__ vtb,
                                                      float* __restrict__ y) {
    __shared__ unsigned short Kl[2][64 * 64];
    __shared__ unsigned short Vl[2][64 * 64];
    __shared__ unsigned short Pl[8 * 16 * 64];
    const int tid = threadIdx.x, l = tid & 63, w = tid >> 6;
    const int bh = blockIdx.x, h = bh & 15;
    const int pair = blockIdx.y;
    const float log2g = log2f(1.0f - exp2f(-5.0f - (float)h));
    char* pw = ((char*)Pl) + w * 2048;
    const int ri = l >> 3;
    const int su = (l & 7) ^ (ri & 7);
    f32x4 zero4 = {0.0f, 0.0f, 0.0f, 0.0f};

    // stage K+V tile at s0 into buffer pb: 2 GLDS16 per thread
    auto STAGE = [&](int s0, int pb) {
        char* kbp = (char*)Kl[pb];
        char* vbp = (char*)Vl[pb];
#pragma unroll
        for (int j = 0; j < 2; ++j) {
            int c = w * 2 + j;
            if (c < 8) {
                const unsigned short* src = kb + (((size_t)bh * kT) + s0 + c * 8 + ri) * kD + su * 8;
                GLDS16(src, kbp + c * 1024);
            } else {
                int cv = c - 8;
                const unsigned short* src = vtb + (((size_t)bh * kD) + cv * 8 + ri) * kT + s0 + su * 8;
                GLDS16(src, vbp + cv * 1024);
            }
        }
    };

#pragma unroll
    for (int half = 0; half < 2; ++half) {
        const int qt = half ? (15 - pair) : pair;
        const int t0 = qt * 128;
        bf16x8 aq0, aq1;
        {
            const unsigned short* qrow = qb + (((size_t)bh * kT) + t0 + w * 16 + (l & 15)) * kD + (l >> 4) * 8;
            aq0 = *(const bf16x8*)(qrow);
            aq1 = *(const bf16x8*)(qrow + 32);
        }
        // materialize q frags + drain (stores from previous half included)
        WAITVM(0);
        asm volatile("" : "+v"(aq0), "+v"(aq1));
        f32x4 accy[4];
#pragma unroll
        for (int j = 0; j < 4; j++) accy[j] = zero4;

        const int nst = 2 * qt + 2;
        STAGE(0, 0);
        for (int st = 0; st < nst; ++st) {
            const int cur = st & 1;
            if (st + 1 < nst) {
                STAGE((st + 1) * 64, cur ^ 1);
                WAITVM(2);
            } else {
                WAITVM(0);
            }
            SCHEDB();
            SBAR();
            char* kbp = (char*)Kl[cur];
            char* vbp = (char*)Vl[cur];
            const int s0 = st * 64;

            // S = Q K^T  (16 rows x 64 cols per wave)
            f32x4 sacc[4];
#pragma unroll
            for (int cb = 0; cb < 4; cb++) sacc[cb] = zero4;
#pragma unroll
            for (int ks = 0; ks < 2; ks++) {
                int kbyte = ks * 64 + (l >> 4) * 16;
#pragma unroll
                for (int cb = 0; cb < 4; cb++) {
                    int row = cb * 16 + (l & 15);
                    bf16x8 bk = *(const bf16x8*)(kbp + row * 128 + (kbyte ^ ((row & 7) << 4)));
                    sacc[cb] = __builtin_amdgcn_mfma_f32_16x16x32_bf16(ks ? aq1 : aq0, bk, sacc[cb], 0, 0, 0);
                }
            }
            // P = S * g^(t0-s0), causal mask on diagonal tiles only
            const float ts = exp2f(log2g * (float)(t0 - s0));
            const bool diag = (st >= 2 * qt);
#pragma unroll
            for (int cb = 0; cb < 4; cb++) {
#pragma unroll
                for (int r = 0; r < 4; r++) {
                    int prow = (l >> 4) * 4 + r;
                    float p = sacc[cb][r] * ts;
                    if (diag) {
                        int rowt = t0 + w * 16 + prow;
                        int sg = s0 + cb * 16 + (l & 15);
                        p = (rowt >= sg) ? p : 0.0f;
                    }
                    int sl = cb * 16 + (l & 15);
                    *(unsigned short*)(pw + prow * 128 + ((sl * 2) ^ ((prow & 7) << 4))) = f2bf(p);
                }
            }
            // O += P V
#pragma unroll
            for (int ks = 0; ks < 2; ks++) {
                int kbyte = ks * 64 + (l >> 4) * 16;
                int prow = l & 15;
                bf16x8 ap = *(const bf16x8*)(pw + prow * 128 + (kbyte ^ ((prow & 7) << 4)));
#pragma unroll
                for (int jb = 0; jb < 4; jb++) {
                    int drow = jb * 16 + (l & 15);
                    bf16x8 bv = *(const bf16x8*)(vbp + drow * 128 + (kbyte ^ ((drow & 7) << 4)));
                    accy[jb] = __builtin_amdgcn_mfma_f32_16x16x32_bf16(ap, bv, accy[jb], 0, 0, 0);
                }
            }
            WAITLG();
            SCHEDB();
            SBAR();
        }
#pragma unroll
        for (int jb = 0; jb < 4; jb++)
#pragma unroll
            for (int r = 0; r < 4; r++) {
                int row = t0 + w * 16 + (l >> 4) * 4 + r;
                int col = jb * 16 + (l & 15);
                y[(((size_t)bh * kT) + row) * kD + col] = accy[jb][r];
            }
    }
}

// ---------------- GroupNorm stats: two-stage ----------------
__global__ __launch_bounds__(256) void gn_part(const float* __restrict__ y,
                                               float* __restrict__ part) {
    int bh = blockIdx.y, seg = blockIdx.x;
    const float4* p = (const float4*)(y + (size_t)bh * (kT * kD) + (size_t)seg * (kT * kD / 8));
    float s = 0.0f, s2 = 0.0f;
    for (int i = threadIdx.x; i < (kT * kD / 8) / 4; i += 256) {
        float4 v = p[i];
        s += v.x + v.y + v.z + v.w;
        s2 += v.x * v.x + v.y * v.y + v.z * v.z + v.w * v.w;
    }
#pragma unroll
    for (int o = 32; o > 0; o >>= 1) {
        s += __shfl_down(s, o);
        s2 += __shfl_down(s2, o);
    }
    __shared__ float red[8];
    int tid = threadIdx.x;
    if ((tid & 63) == 0) {
        red[(tid >> 6) * 2] = s;
        red[(tid >> 6) * 2 + 1] = s2;
    }
    __syncthreads();
    if (tid == 0) {
        float S = 0.0f, S2 = 0.0f;
#pragma unroll
        for (int i = 0; i < 4; i++) { S += red[2 * i]; S2 += red[2 * i + 1]; }
        part[(bh * 8 + seg) * 2] = S;
        part[(bh * 8 + seg) * 2 + 1] = S2;
    }
}

__global__ __launch_bounds__(64) void gn_fin(const float* __restrict__ part,
                                             float* __restrict__ stats) {
    int bh = threadIdx.x;
    if (bh >= kB * kH) return;
    float S = 0.0f, S2 = 0.0f;
#pragma unroll
    for (int i = 0; i < 8; i++) {
        S += part[(bh * 8 + i) * 2];
        S2 += part[(bh * 8 + i) * 2 + 1];
    }
    const float inv = 1.0f / (float)(kT * kD);
    float mean = S * inv;
    float var = S2 * inv - mean * mean;
    stats[2 * bh] = mean;
    stats[2 * bh + 1] = rsqrtf(var + 1e-5f);
}

// ---------------- z = bf16( silu(g) * ((y - mean)*rstd*gw + gb) ) ----------------
__global__ __launch_bounds__(256) void fuse_z(const float* __restrict__ g,
                                              const float* __restrict__ y,
                                              const float* __restrict__ stats,
                                              const float* __restrict__ gnw,
                                              const float* __restrict__ gnb,
                                              unsigned short* __restrict__ z) {
    int idx = blockIdx.x * 256 + threadIdx.x;  // (B*T*C)/4
    int row = idx >> 8;
    int c = (idx & 255) << 2;
    int b = row >> 11, t = row & 2047;
    int h = c >> 6, d = c & 63;
    int bh = b * kH + h;
    float4 gv = *(const float4*)(g + (size_t)row * kC + c);
    float4 yv = *(const float4*)(y + (((size_t)bh * kT) + t) * kD + d);
    float mean = stats[2 * bh], rstd = stats[2 * bh + 1];
    float4 wv = *(const float4*)(gnw + c);
    float4 bv = *(const float4*)(gnb + c);
    float s0 = gv.x / (1.0f + expf(-gv.x));
    float s1 = gv.y / (1.0f + expf(-gv.y));
    float s2 = gv.z / (1.0f + expf(-gv.z));
    float s3 = gv.w / (1.0f + expf(-gv.w));
    u16x4 o;
    o[0] = f2bf(s0 * ((yv.x - mean) * rstd * wv.x + bv.x));
    o[1] = f2bf(s1 * ((yv.y - mean) * rstd * wv.y + bv.y));
    o[2] = f2bf(s2 * ((yv.z - mean) * rstd * wv.z + bv.z));
    o[3] = f2bf(s3 * ((yv.w - mean) * rstd * wv.w + bv.w));
    *(u16x4*)(z + (size_t)row * kC + c) = o;
}

extern "C" void kernel_launch(void* const* d_in, const int* in_sizes, int n_in,
                              void* d_out, int out_size, void* d_ws, size_t ws_size,
                              hipStream_t stream) {
    const float* x = (const float*)d_in[0];
    const float* w_qkv = (const float*)d_in[1];
    const float* w_gated = (const float*)d_in[2];
    const float* w_proj = (const float*)d_in[3];
    const float* gnw = (const float*)d_in[4];
    const float* gnb = (const float*)d_in[5];
    float* out = (float*)d_out;
    char* ws = (char*)d_ws;

    unsigned short* xb      = (unsigned short*)(ws + 0);         // 8 MB
    unsigned short* wqkvb   = (unsigned short*)(ws + 8388608);   // 6 MB
    unsigned short* wgatedb = (unsigned short*)(ws + 14680064);  // 2 MB
    unsigned short* wprojb  = (unsigned short*)(ws + 16777216);  // 2 MB
    unsigned short* qb      = (unsigned short*)(ws + 18874368);  // 8 MB (B,H,T,D) pre-scaled
    unsigned short* kbuf    = (unsigned short*)(ws + 27262976);  // 8 MB (B,H,T,D) pre-scaled
    unsigned short* vtb     = (unsigned short*)(ws + 35651584);  // 8 MB (B,H,D,T)
    unsigned short* zb      = (unsigned short*)(ws + 44040192);  // 8 MB
    float* cosT  = (float*)(ws + 52428800);                      // 256 KB
    float* sinT  = (float*)(ws + 52690944);                      // 256 KB
    float* sclT  = (float*)(ws + 52953088);                      // 256 KB
    float* stats = (float*)(ws + 53215232);                      // 256 B
    float* tmp0  = (float*)(ws + 53215488);                      // 32 MB: qk fp32
    float* tmpY  = tmp0;                                         // 16 MB: v fp32, then y
    float* tmpG  = tmp0 + 4194304;                               // 16 MB: g fp32
    float* part  = (float*)(ws + 44040192);                      // gn partials (zb region, free until fuse_z)

    cvt_bf16<<<4096, 256, 0, stream>>>(x, xb, kB * kT * kC);
    cvt_bf16<<<3072, 256, 0, stream>>>(w_qkv, wqkvb, 3 * kC * kC);
    cvt_bf16<<<1024, 256, 0, stream>>>(w_gated, wgatedb, kC * kC);
    cvt_bf16<<<1024, 256, 0, stream>>>(w_proj, wprojb, kC * kC);
    rope_tables<<<256, 256, 0, stream>>>(cosT, sinT, sclT);

    // fused q|k GEMM: (4096 x 2048) = x @ [wq; wk]^T
    gemm128<<<dim3(2048 / 128, 4096 / 128), 256, 0, stream>>>(xb, wqkvb, tmp0, 2048, kC);
    rope_qk<<<8192, 256, 0, stream>>>(tmp0, cosT, sinT, sclT, qb, kbuf);

    // v GEMM -> fp32, then transpose to (B,H,D,T)
    gemm128<<<dim3(kC / 128, 4096 / 128), 256, 0, stream>>>(xb, wqkvb + (size_t)2 * kC * kC, tmpY, kC, kC);
    vt_from_f32<<<dim3(kT / 64, kB * kH), 256, 0, stream>>>(tmpY, vtb);

    // retention attention -> y fp32 (B,H,T,D) into tmpY
    retention_attn<<<dim3(kB * kH, 8), 512, 0, stream>>>(qb, kbuf, vtb, tmpY);

    gn_part<<<dim3(8, kB * kH), 256, 0, stream>>>(tmpY, part);
    gn_fin<<<1, 64, 0, stream>>>(part, stats);

    // gated branch
    gemm128<<<dim3(kC / 128, 4096 / 128), 256, 0, stream>>>(xb, wgatedb, tmpG, kC, kC);
    fuse_z<<<4096, 256, 0, stream>>>(tmpG, tmpY, stats, gnw, gnb, zb);

    // proj -> out
    gemm128<<<dim3(kC / 128, 4096 / 128), 256, 0, stream>>>(zb, wprojb, out, kC, kC);
}

// Round 5
// 161.621 us; speedup vs baseline: 1.1430x; 1.1430x over previous
//
#include <hip/hip_runtime.h>

typedef __attribute__((ext_vector_type(8))) short bf16x8;
typedef __attribute__((ext_vector_type(4))) float f32x4;
typedef __attribute__((ext_vector_type(16))) float f32x16;
typedef __attribute__((ext_vector_type(2))) unsigned short u16x2;
typedef __attribute__((ext_vector_type(4))) unsigned short u16x4;
typedef __attribute__((ext_vector_type(2))) unsigned int u32x2;

static constexpr int kB = 2;
static constexpr int kT = 2048;
static constexpr int kC = 1024;
static constexpr int kH = 16;
static constexpr int kD = 64;
static constexpr int kCH = 128;   // chunk length
static constexpr int kNC = kT / kCH;  // 16 chunks

__device__ inline unsigned short f2bf(float f) {
    unsigned int u = __float_as_uint(f);
    u += 0x7FFFu + ((u >> 16) & 1u);
    return (unsigned short)(u >> 16);
}

#define GLDS16(g, s)                                                            \
    __builtin_amdgcn_global_load_lds(                                           \
        (const __attribute__((address_space(1))) unsigned int*)(g),             \
        (__attribute__((address_space(3))) unsigned int*)(s), 16, 0, 0)

// ---------------- f32 -> bf16 convert ----------------
__global__ __launch_bounds__(256) void cvt_bf16(const float* __restrict__ in,
                                                unsigned short* __restrict__ out, int n) {
    int i = (blockIdx.x * 256 + threadIdx.x) * 4;
    if (i >= n) return;
    float4 v = *(const float4*)(in + i);
    u16x4 o;
    o[0] = f2bf(v.x); o[1] = f2bf(v.y); o[2] = f2bf(v.z); o[3] = f2bf(v.w);
    *(u16x4*)(out + i) = o;
}

// ---------------- RoPE/xPos tables ----------------
__global__ __launch_bounds__(256) void rope_tables(float* __restrict__ ct,
                                                   float* __restrict__ st,
                                                   float* __restrict__ sc) {
    int idx = blockIdx.x * 256 + threadIdx.x;
    if (idx >= kT * 32) return;
    int t = idx >> 5, i = idx & 31;
    float half = 2.0f * (float)i;
    float inv_freq = powf(10000.0f, -half / 64.0f);
    float fr = (float)t * inv_freq;
    float sv = (half + 0.4f * 64.0f) / (1.4f * 64.0f);
    float p = ((float)t - 1024.0f) / 512.0f;
    ct[idx] = cosf(fr);
    st[idx] = sinf(fr);
    sc[idx] = powf(sv, p);
}

// ---------------- bf16 MFMA GEMM: C[M,N] = A[M,K] * Bm[N,K]^T, fp32 out ----------
// (r3 proven structure) tile 128 x TN, BK=64, 4 waves. global_load_lds staging with
// pre-swizzled global source; LDS reads XOR-swizzled -> conflict-free ds_read_b128.
template <int TN>
__global__ __launch_bounds__(256) void gemm_bt(const unsigned short* __restrict__ A,
                                               const unsigned short* __restrict__ Bm,
                                               float* __restrict__ Cm,
                                               int N, int K) {
    constexpr int NF = TN / 32;
    constexpr int CH = 16 + TN / 8;
    __shared__ __align__(16) unsigned short Al[128 * 64];
    __shared__ __align__(16) unsigned short Bl[TN * 64];
    char* ab = (char*)Al;
    char* bb = (char*)Bl;
    const int tid = threadIdx.x;
    const int l = tid & 63, w = tid >> 6;
    const int wr = w >> 1, wc = w & 1;
    const int tm = blockIdx.y * 128, tn = blockIdx.x * TN;
    const int ri = l >> 3;
    const int su = (l & 7) ^ (ri & 7);

    f32x4 zero4 = {0.0f, 0.0f, 0.0f, 0.0f};
    f32x4 acc[4][NF];
#pragma unroll
    for (int m = 0; m < 4; m++)
#pragma unroll
        for (int n = 0; n < NF; n++) acc[m][n] = zero4;

    for (int kt = 0; kt < K; kt += 64) {
#pragma unroll
        for (int c = w; c < CH; c += 4) {
            if (c < 16) {
                const unsigned short* src = A + (size_t)(tm + c * 8 + ri) * K + kt + su * 8;
                GLDS16(src, ab + c * 1024);
            } else {
                int cb = c - 16;
                const unsigned short* src = Bm + (size_t)(tn + cb * 8 + ri) * K + kt + su * 8;
                GLDS16(src, bb + cb * 1024);
            }
        }
        __syncthreads();
#pragma unroll
        for (int ks = 0; ks < 2; ks++) {
            bf16x8 af[4], bfr[NF];
            int kbyte = ks * 64 + (l >> 4) * 16;
#pragma unroll
            for (int m = 0; m < 4; m++) {
                int row = wr * 64 + m * 16 + (l & 15);
                af[m] = *(const bf16x8*)(ab + row * 128 + (kbyte ^ ((row & 7) << 4)));
            }
#pragma unroll
            for (int n = 0; n < NF; n++) {
                int row = wc * (TN / 2) + n * 16 + (l & 15);
                bfr[n] = *(const bf16x8*)(bb + row * 128 + (kbyte ^ ((row & 7) << 4)));
            }
#pragma unroll
            for (int m = 0; m < 4; m++)
#pragma unroll
                for (int n = 0; n < NF; n++)
                    acc[m][n] = __builtin_amdgcn_mfma_f32_16x16x32_bf16(af[m], bfr[n], acc[m][n], 0, 0, 0);
        }
        __syncthreads();
    }
#pragma unroll
    for (int m = 0; m < 4; m++)
#pragma unroll
        for (int n = 0; n < NF; n++)
#pragma unroll
            for (int r = 0; r < 4; r++) {
                int row = tm + wr * 64 + m * 16 + (l >> 4) * 4 + r;
                int col = tn + wc * (TN / 2) + n * 16 + (l & 15);
                Cm[(size_t)row * N + col] = acc[m][n][r];
            }
}

// ---------------- RoPE q+k fused; decay pre-scales for chunk=128 -------------
// dq scaled by 0.125 * g^(t&127); dk scaled by g^(-(t&127)).
__global__ __launch_bounds__(256) void rope_qk(const float* __restrict__ src,
                                               const float* __restrict__ ct,
                                               const float* __restrict__ st,
                                               const float* __restrict__ sc,
                                               unsigned short* __restrict__ dq,
                                               unsigned short* __restrict__ dk) {
    int idx = blockIdx.x * 256 + threadIdx.x;  // B*T*H*32
    if (idx >= kB * kT * kH * 32) return;
    int i = idx & 31;
    int h = (idx >> 5) & 15;
    int t = (idx >> 9) & 2047;
    int b = idx >> 20;
    size_t row = (size_t)(b * kT + t) * 2048;
    float2 qv = *(const float2*)(src + row + h * kD + 2 * i);
    float2 kv = *(const float2*)(src + row + 1024 + h * kD + 2 * i);
    int ti = t * 32 + i;
    float c = ct[ti], s = st[ti], sv = sc[ti];
    float log2g = log2f(1.0f - exp2f(-5.0f - (float)h));
    float qdec = 0.125f * exp2f(log2g * (float)(t & 127));
    float kdec = exp2f(-log2g * (float)(t & 127));
    float cq = c * sv, sq = s * sv;
    float ck = c / sv, sk = s / sv;
    float q0 = (qv.x * cq - qv.y * sq) * qdec;
    float q1 = (qv.y * cq + qv.x * sq) * qdec;
    float k0 = (kv.x * ck - kv.y * sk) * kdec;
    float k1 = (kv.y * ck + kv.x * sk) * kdec;
    size_t doff = (((size_t)(b * kH + h) * kT + t) * kD) + 2 * i;
    u16x2 oq, ok;
    oq[0] = f2bf(q0); oq[1] = f2bf(q1);
    ok[0] = f2bf(k0); ok[1] = f2bf(k1);
    *(u16x2*)(dq + doff) = oq;
    *(u16x2*)(dk + doff) = ok;
}

// ---------------- V: fp32 (B*T, C) -> bf16 transposed (B,H,D,T) ----------------
__global__ __launch_bounds__(256) void vt_from_f32(const float* __restrict__ vf,
                                                   unsigned short* __restrict__ vtb) {
    __shared__ unsigned short tile[64][72];
    int tt = blockIdx.x * 64;
    int bh = blockIdx.y;
    int b = bh >> 4, h = bh & 15;
    int r = threadIdx.x >> 2;
    int cu = (threadIdx.x & 3) * 16;
    const float* srow = vf + ((size_t)(b * kT) + tt + r) * kC + h * kD + cu;
#pragma unroll
    for (int j = 0; j < 16; j += 4) {
        float4 v = *(const float4*)(srow + j);
        tile[r][cu + j + 0] = f2bf(v.x);
        tile[r][cu + j + 1] = f2bf(v.y);
        tile[r][cu + j + 2] = f2bf(v.z);
        tile[r][cu + j + 3] = f2bf(v.w);
    }
    __syncthreads();
    int d = threadIdx.x >> 2;
    int tb = (threadIdx.x & 3) * 16;
    bf16x8 o0, o1;
#pragma unroll
    for (int e = 0; e < 8; e++) {
        o0[e] = (short)tile[tb + e][d];
        o1[e] = (short)tile[tb + 8 + e][d];
    }
    unsigned short* drow = vtb + ((size_t)bh * kD + d) * kT + tt + tb;
    *(bf16x8*)(drow) = o0;
    *(bf16x8*)(drow + 8) = o1;
}

// ---------------- K: bf16 (B,H,T,D) -> bf16 transposed (B,H,D,T) ----------------
__global__ __launch_bounds__(256) void kt_bf16(const unsigned short* __restrict__ kb,
                                               unsigned short* __restrict__ ktb) {
    __shared__ unsigned short tile[64][72];
    int tt = blockIdx.x * 64;
    int bh = blockIdx.y;
    int r = threadIdx.x >> 2;
    int cu = (threadIdx.x & 3) * 16;
    const unsigned short* srow = kb + ((size_t)bh * kT + tt + r) * kD + cu;
    bf16x8 i0 = *(const bf16x8*)(srow);
    bf16x8 i1 = *(const bf16x8*)(srow + 8);
#pragma unroll
    for (int e = 0; e < 8; e++) {
        tile[r][cu + e] = (unsigned short)i0[e];
        tile[r][cu + 8 + e] = (unsigned short)i1[e];
    }
    __syncthreads();
    int d = threadIdx.x >> 2;
    int tb = (threadIdx.x & 3) * 16;
    bf16x8 o0, o1;
#pragma unroll
    for (int e = 0; e < 8; e++) {
        o0[e] = (short)tile[tb + e][d];
        o1[e] = (short)tile[tb + 8 + e][d];
    }
    unsigned short* drow = ktb + ((size_t)bh * kD + d) * kT + tt + tb;
    *(bf16x8*)(drow) = o0;
    *(bf16x8*)(drow + 8) = o1;
}

// ---------------- chunk_m: Mt[bh][c] = g^128 * (V_c^T K~_c) as M^T[d2][d1], bf16 ----
// grid (16 c, 32 bh), 256 thr = 4 waves (iw = d2-tile, jw = d1-tile), 32x32 MFMA.
__global__ __launch_bounds__(256) void chunk_m(const unsigned short* __restrict__ ktb,
                                               const unsigned short* __restrict__ vtb,
                                               unsigned short* __restrict__ Mt) {
    __shared__ __align__(16) unsigned short Ktl[64 * 128];  // [d1 64][s 128]
    __shared__ __align__(16) unsigned short Vtl[64 * 128];  // [d2 64][s 128]
    const int tid = threadIdx.x, l = tid & 63, w = tid >> 6;
    const int c = blockIdx.x, bh = blockIdx.y, h = bh & 15;
    const int ql = l & 31, hi5 = l >> 5;
    char* kp = (char*)Ktl;
    char* vp = (char*)Vtl;
#pragma unroll
    for (int j = 0; j < 4; ++j) {
        int ch = w * 4 + j;
        int row = ch * 4 + (l >> 4);
        int u = (l & 15) ^ (row & 15);
        GLDS16(ktb + ((size_t)bh * kD + row) * kT + c * 128 + u * 8, kp + ch * 1024);
        GLDS16(vtb + ((size_t)bh * kD + row) * kT + c * 128 + u * 8, vp + ch * 1024);
    }
    __syncthreads();
    const int iw = w >> 1, jw = w & 1;
    f32x16 acc;
#pragma unroll
    for (int r = 0; r < 16; ++r) acc[r] = 0.0f;
#pragma unroll
    for (int sk = 0; sk < 8; ++sk) {
        int rowa = iw * 32 + ql;
        int rowb = jw * 32 + ql;
        bf16x8 av = *(const bf16x8*)(vp + rowa * 256 + 16 * ((2 * sk + hi5) ^ (rowa & 15)));
        bf16x8 bk = *(const bf16x8*)(kp + rowb * 256 + 16 * ((2 * sk + hi5) ^ (rowb & 15)));
        acc = __builtin_amdgcn_mfma_f32_32x32x16_bf16(av, bk, acc, 0, 0, 0);
    }
    float log2g = log2f(1.0f - exp2f(-5.0f - (float)h));
    float gC = exp2f(128.0f * log2g);
    unsigned short* mo = Mt + ((size_t)(bh * kNC + c)) * 4096;
#pragma unroll
    for (int r = 0; r < 16; ++r) {
        int row = iw * 32 + (r & 3) + 8 * (r >> 2) + 4 * hi5;
        int col = jw * 32 + ql;
        mo[row * 64 + col] = f2bf(acc[r] * gC);
    }
}

// ---------------- chunk_states: St[bh][c] = sum_{j<c} gC^(c-1-j) Mt[bh][j], bf16 ----
__global__ __launch_bounds__(256) void chunk_states(const unsigned short* __restrict__ Mt,
                                                    unsigned short* __restrict__ St) {
    const int c = blockIdx.x, bh = blockIdx.y, h = bh & 15;
    const int tid = threadIdx.x;
    float log2g = log2f(1.0f - exp2f(-5.0f - (float)h));
    float gC = exp2f(128.0f * log2g);
    float acc[16];
#pragma unroll
    for (int e = 0; e < 16; ++e) acc[e] = 0.0f;
    for (int j = 0; j < c; ++j) {
        const unsigned short* m = Mt + ((size_t)(bh * kNC + j)) * 4096;
#pragma unroll
        for (int k = 0; k < 4; ++k) {
            u16x4 v = *(const u16x4*)(m + (k * 256 + tid) * 4);
#pragma unroll
            for (int e = 0; e < 4; ++e) {
                float f = __uint_as_float(((unsigned int)(unsigned short)v[e]) << 16);
                acc[k * 4 + e] = acc[k * 4 + e] * gC + f;
            }
        }
    }
    unsigned short* so = St + ((size_t)(bh * kNC + c)) * 4096;
#pragma unroll
    for (int k = 0; k < 4; ++k) {
        u16x4 o;
#pragma unroll
        for (int e = 0; e < 4; ++e) o[e] = f2bf(acc[k * 4 + e]);
        *(u16x4*)(so + (k * 256 + tid) * 4) = o;
    }
}

// ---------------- chunk_attn: y_c = mask(Q~K~^T) V + Q~ S_c ----------------
// grid (16 c, 32 bh), 512 thr = 8 waves (qw = w>>1 over 4 q-subtiles, dw = w&1).
__global__ __launch_bounds__(512) void chunk_attn(const unsigned short* __restrict__ qb,
                                                  const unsigned short* __restrict__ kb,
                                                  const unsigned short* __restrict__ vtb,
                                                  const unsigned short* __restrict__ St,
                                                  float* __restrict__ y) {
    __shared__ __align__(16) unsigned short Kt[128 * 64];   // [t-local 128][d 64]
    __shared__ __align__(16) unsigned short Vt[64 * 128];   // [d2 64][s 128]
    __shared__ __align__(16) unsigned short Ss[64 * 64];    // [d2 64][d1 64]
    __shared__ __align__(16) unsigned short Pl[8 * 32 * 64]; // per-wave 32 x 128B
    const int tid = threadIdx.x, l = tid & 63, w = tid >> 6;
    const int c = blockIdx.x, bh = blockIdx.y;
    const int qw = w >> 1, dw = w & 1;
    const int ql = l & 31, hi5 = l >> 5;
    char* kp = (char*)Kt;
    char* vp = (char*)Vt;
    char* sp = (char*)Ss;
    char* pw = (char*)Pl + w * 4096;

    // staging: K 16 chunks, V 16 chunks, S 8 chunks (5 GLDS16/thread)
#pragma unroll
    for (int j = 0; j < 2; ++j) {
        int ch = w * 2 + j;
        int row = ch * 8 + (l >> 3);
        int u = (l & 7) ^ (row & 7);
        GLDS16(kb + ((size_t)bh * kT + c * 128 + row) * kD + u * 8, kp + ch * 1024);
    }
#pragma unroll
    for (int j = 0; j < 2; ++j) {
        int ch = w * 2 + j;
        int row = ch * 4 + (l >> 4);
        int u = (l & 15) ^ (row & 15);
        GLDS16(vtb + ((size_t)bh * kD + row) * kT + c * 128 + u * 8, vp + ch * 1024);
    }
    {
        int row = w * 8 + (l >> 3);
        int u = (l & 7) ^ (row & 7);
        GLDS16(St + ((size_t)(bh * kNC + c)) * 4096 + row * 64 + u * 8, sp + w * 1024);
    }
    // Q fragments (direct global, 4 dk slices)
    bf16x8 aq[4];
    {
        const unsigned short* qrow = qb + ((size_t)bh * kT + c * 128 + qw * 32 + ql) * kD + hi5 * 8;
#pragma unroll
        for (int dk = 0; dk < 4; ++dk) aq[dk] = *(const bf16x8*)(qrow + dk * 16);
    }
    __syncthreads();

    f32x16 acc;
#pragma unroll
    for (int r = 0; r < 16; ++r) acc[r] = 0.0f;
    const int qidx = qw * 32 + ql;

#pragma unroll
    for (int p = 0; p < 2; ++p) {
        // intra scores (swapped): sacc[sb2] = S^T tile, lane holds P[q=ql][s]
        f32x16 sA, sB;
#pragma unroll
        for (int r = 0; r < 16; ++r) { sA[r] = 0.0f; sB[r] = 0.0f; }
#pragma unroll
        for (int dk = 0; dk < 4; ++dk) {
            int rowa = (2 * p) * 32 + ql;
            int rowb = (2 * p + 1) * 32 + ql;
            bf16x8 ka = *(const bf16x8*)(kp + rowa * 128 + 16 * ((2 * dk + hi5) ^ (rowa & 7)));
            bf16x8 kb2 = *(const bf16x8*)(kp + rowb * 128 + 16 * ((2 * dk + hi5) ^ (rowb & 7)));
            sA = __builtin_amdgcn_mfma_f32_32x32x16_bf16(ka, aq[dk], sA, 0, 0, 0);
            sB = __builtin_amdgcn_mfma_f32_32x32x16_bf16(kb2, aq[dk], sB, 0, 0, 0);
        }
        // mask + pack to bf16 pairs + write per-wave P rows (swizzled)
#pragma unroll
        for (int sb2 = 0; sb2 < 2; ++sb2) {
            int sbase = (2 * p + sb2) * 32 + 4 * hi5;
#pragma unroll
            for (int m = 0; m < 4; ++m) {
                float v0, v1, v2, v3;
                {
                    int s0i = sbase + 8 * m;
                    float x0 = sb2 ? sB[4 * m + 0] : sA[4 * m + 0];
                    float x1 = sb2 ? sB[4 * m + 1] : sA[4 * m + 1];
                    float x2 = sb2 ? sB[4 * m + 2] : sA[4 * m + 2];
                    float x3 = sb2 ? sB[4 * m + 3] : sA[4 * m + 3];
                    v0 = (qidx >= s0i + 0) ? x0 : 0.0f;
                    v1 = (qidx >= s0i + 1) ? x1 : 0.0f;
                    v2 = (qidx >= s0i + 2) ? x2 : 0.0f;
                    v3 = (qidx >= s0i + 3) ? x3 : 0.0f;
                }
                unsigned int lo, hi;
                asm("v_cvt_pk_bf16_f32 %0, %1, %2" : "=v"(lo) : "v"(v0), "v"(v1));
                asm("v_cvt_pk_bf16_f32 %0, %1, %2" : "=v"(hi) : "v"(v2), "v"(v3));
                u32x2 pr; pr[0] = lo; pr[1] = hi;
                *(u32x2*)(pw + ql * 128 + (((sb2 * 4 + m) * 16) ^ ((ql & 7) << 4)) + hi5 * 8) = pr;
            }
        }
        // PV for kk = 4p..4p+3
#pragma unroll
        for (int kki = 0; kki < 4; ++kki) {
            bf16x8 ap = *(const bf16x8*)(pw + ql * 128 + 16 * ((2 * kki + hi5) ^ (ql & 7)));
            int rowv = dw * 32 + ql;
            bf16x8 bv = *(const bf16x8*)(vp + rowv * 256 + 16 * ((2 * (4 * p + kki) + hi5) ^ (rowv & 15)));
            acc = __builtin_amdgcn_mfma_f32_32x32x16_bf16(ap, bv, acc, 0, 0, 0);
        }
    }
    // inter: y += Q~ @ S_c   (a = Q rows, b = S^T rows)
#pragma unroll
    for (int dk = 0; dk < 4; ++dk) {
        int rows = dw * 32 + ql;
        bf16x8 bs = *(const bf16x8*)(sp + rows * 128 + 16 * ((2 * dk + hi5) ^ (rows & 7)));
        acc = __builtin_amdgcn_mfma_f32_32x32x16_bf16(aq[dk], bs, acc, 0, 0, 0);
    }
    // write y (B,H,T,D) fp32
#pragma unroll
    for (int r = 0; r < 16; ++r) {
        int row = c * 128 + qw * 32 + (r & 3) + 8 * (r >> 2) + 4 * hi5;
        int col = dw * 32 + ql;
        y[((size_t)bh * kT + row) * kD + col] = acc[r];
    }
}

// ---------------- GroupNorm stats: two-stage ----------------
__global__ __launch_bounds__(256) void gn_part(const float* __restrict__ y,
                                               float* __restrict__ part) {
    int bh = blockIdx.y, seg = blockIdx.x;
    const float4* p = (const float4*)(y + (size_t)bh * (kT * kD) + (size_t)seg * (kT * kD / 8));
    float s = 0.0f, s2 = 0.0f;
    for (int i = threadIdx.x; i < (kT * kD / 8) / 4; i += 256) {
        float4 v = p[i];
        s += v.x + v.y + v.z + v.w;
        s2 += v.x * v.x + v.y * v.y + v.z * v.z + v.w * v.w;
    }
#pragma unroll
    for (int o = 32; o > 0; o >>= 1) {
        s += __shfl_down(s, o);
        s2 += __shfl_down(s2, o);
    }
    __shared__ float red[8];
    int tid = threadIdx.x;
    if ((tid & 63) == 0) {
        red[(tid >> 6) * 2] = s;
        red[(tid >> 6) * 2 + 1] = s2;
    }
    __syncthreads();
    if (tid == 0) {
        float S = 0.0f, S2 = 0.0f;
#pragma unroll
        for (int i = 0; i < 4; i++) { S += red[2 * i]; S2 += red[2 * i + 1]; }
        part[(bh * 8 + seg) * 2] = S;
        part[(bh * 8 + seg) * 2 + 1] = S2;
    }
}

__global__ __launch_bounds__(64) void gn_fin(const float* __restrict__ part,
                                             float* __restrict__ stats) {
    int bh = threadIdx.x;
    if (bh >= kB * kH) return;
    float S = 0.0f, S2 = 0.0f;
#pragma unroll
    for (int i = 0; i < 8; i++) {
        S += part[(bh * 8 + i) * 2];
        S2 += part[(bh * 8 + i) * 2 + 1];
    }
    const float inv = 1.0f / (float)(kT * kD);
    float mean = S * inv;
    float var = S2 * inv - mean * mean;
    stats[2 * bh] = mean;
    stats[2 * bh + 1] = rsqrtf(var + 1e-5f);
}

// ---------------- z = bf16( silu(g) * ((y - mean)*rstd*gw + gb) ) ----------------
__global__ __launch_bounds__(256) void fuse_z(const float* __restrict__ g,
                                              const float* __restrict__ y,
                                              const float* __restrict__ stats,
                                              const float* __restrict__ gnw,
                                              const float* __restrict__ gnb,
                                              unsigned short* __restrict__ z) {
    int idx = blockIdx.x * 256 + threadIdx.x;  // (B*T*C)/4
    int row = idx >> 8;
    int c = (idx & 255) << 2;
    int b = row >> 11, t = row & 2047;
    int h = c >> 6, d = c & 63;
    int bh = b * kH + h;
    float4 gv = *(const float4*)(g + (size_t)row * kC + c);
    float4 yv = *(const float4*)(y + (((size_t)bh * kT) + t) * kD + d);
    float mean = stats[2 * bh], rstd = stats[2 * bh + 1];
    float4 wv = *(const float4*)(gnw + c);
    float4 bv = *(const float4*)(gnb + c);
    float s0 = gv.x / (1.0f + expf(-gv.x));
    float s1 = gv.y / (1.0f + expf(-gv.y));
    float s2 = gv.z / (1.0f + expf(-gv.z));
    float s3 = gv.w / (1.0f + expf(-gv.w));
    u16x4 o;
    o[0] = f2bf(s0 * ((yv.x - mean) * rstd * wv.x + bv.x));
    o[1] = f2bf(s1 * ((yv.y - mean) * rstd * wv.y + bv.y));
    o[2] = f2bf(s2 * ((yv.z - mean) * rstd * wv.z + bv.z));
    o[3] = f2bf(s3 * ((yv.w - mean) * rstd * wv.w + bv.w));
    *(u16x4*)(z + (size_t)row * kC + c) = o;
}

extern "C" void kernel_launch(void* const* d_in, const int* in_sizes, int n_in,
                              void* d_out, int out_size, void* d_ws, size_t ws_size,
                              hipStream_t stream) {
    const float* x = (const float*)d_in[0];
    const float* w_qkv = (const float*)d_in[1];
    const float* w_gated = (const float*)d_in[2];
    const float* w_proj = (const float*)d_in[3];
    const float* gnw = (const float*)d_in[4];
    const float* gnb = (const float*)d_in[5];
    float* out = (float*)d_out;
    char* ws = (char*)d_ws;

    unsigned short* xb      = (unsigned short*)(ws + 0);         // 8 MB
    unsigned short* wqkvb   = (unsigned short*)(ws + 8388608);   // 6 MB
    unsigned short* wgatedb = (unsigned short*)(ws + 14680064);  // 2 MB
    unsigned short* wprojb  = (unsigned short*)(ws + 16777216);  // 2 MB
    unsigned short* qb      = (unsigned short*)(ws + 18874368);  // 8 MB (B,H,T,D) pre-scaled
    unsigned short* kbuf    = (unsigned short*)(ws + 27262976);  // 8 MB (B,H,T,D) pre-scaled
    unsigned short* vtb     = (unsigned short*)(ws + 35651584);  // 8 MB (B,H,D,T)
    unsigned short* zb      = (unsigned short*)(ws + 44040192);  // 8 MB
    float* cosT  = (float*)(ws + 52428800);                      // 256 KB
    float* sinT  = (float*)(ws + 52690944);                      // 256 KB
    float* sclT  = (float*)(ws + 52953088);                      // 256 KB
    float* stats = (float*)(ws + 53215232);                      // 256 B
    float* tmp0  = (float*)(ws + 53215488);                      // 32 MB: qk fp32
    float* tmpY  = tmp0;                                         // 16 MB: v fp32, then y
    float* tmpG  = tmp0 + 4194304;                               // 16 MB: ktb/Mt/St, later g fp32
    unsigned short* ktb = (unsigned short*)(ws + 69992704);      // 8 MB (B,H,D,T)
    unsigned short* Mt  = (unsigned short*)(ws + 78381312);      // 4 MB bf16 M^T per (bh,c)
    unsigned short* St  = (unsigned short*)(ws + 82575616);      // 4 MB bf16 S^T per (bh,c)
    float* part  = (float*)(ws + 44040192);                      // gn partials (zb region)

    cvt_bf16<<<4096, 256, 0, stream>>>(x, xb, kB * kT * kC);
    cvt_bf16<<<3072, 256, 0, stream>>>(w_qkv, wqkvb, 3 * kC * kC);
    cvt_bf16<<<1024, 256, 0, stream>>>(w_gated, wgatedb, kC * kC);
    cvt_bf16<<<1024, 256, 0, stream>>>(w_proj, wprojb, kC * kC);
    rope_tables<<<256, 256, 0, stream>>>(cosT, sinT, sclT);

    // fused q|k GEMM: (4096 x 2048) = x @ [wq; wk]^T
    gemm_bt<128><<<dim3(2048 / 128, 4096 / 128), 256, 0, stream>>>(xb, wqkvb, tmp0, 2048, kC);
    rope_qk<<<8192, 256, 0, stream>>>(tmp0, cosT, sinT, sclT, qb, kbuf);

    // v GEMM -> fp32, transpose to (B,H,D,T)
    gemm_bt<64><<<dim3(kC / 64, 4096 / 128), 256, 0, stream>>>(xb, wqkvb + (size_t)2 * kC * kC, tmpY, kC, kC);
    vt_from_f32<<<dim3(kT / 64, kB * kH), 256, 0, stream>>>(tmpY, vtb);

    // k transpose -> (B,H,D,T)
    kt_bf16<<<dim3(kT / 64, kB * kH), 256, 0, stream>>>(kbuf, ktb);

    // chunked retention
    chunk_m<<<dim3(kNC, kB * kH), 256, 0, stream>>>(ktb, vtb, Mt);
    chunk_states<<<dim3(kNC, kB * kH), 256, 0, stream>>>(Mt, St);
    chunk_attn<<<dim3(kNC, kB * kH), 512, 0, stream>>>(qb, kbuf, vtb, St, tmpY);

    gn_part<<<dim3(8, kB * kH), 256, 0, stream>>>(tmpY, part);
    gn_fin<<<1, 64, 0, stream>>>(part, stats);

    // gated branch
    gemm_bt<64><<<dim3(kC / 64, 4096 / 128), 256, 0, stream>>>(xb, wgatedb, tmpG, kC, kC);
    fuse_z<<<4096, 256, 0, stream>>>(tmpG, tmpY, stats, gnw, gnb, zb);

    // proj -> out
    gemm_bt<64><<<dim3(kC / 64, 4096 / 128), 256, 0, stream>>>(zb, wprojb, out, kC, kC);
}

// Round 6
// 147.222 us; speedup vs baseline: 1.2548x; 1.0978x over previous
//
#include <hip/hip_runtime.h>

typedef __attribute__((ext_vector_type(8))) short bf16x8;
typedef __attribute__((ext_vector_type(4))) float f32x4;
typedef __attribute__((ext_vector_type(16))) float f32x16;
typedef __attribute__((ext_vector_type(2))) unsigned short u16x2;
typedef __attribute__((ext_vector_type(4))) unsigned short u16x4;
typedef __attribute__((ext_vector_type(2))) unsigned int u32x2;

static constexpr int kB = 2;
static constexpr int kT = 2048;
static constexpr int kC = 1024;
static constexpr int kH = 16;
static constexpr int kD = 64;
static constexpr int kNC = 16;  // chunks of 128

__device__ inline unsigned short f2bf(float f) {
    unsigned int u = __float_as_uint(f);
    u += 0x7FFFu + ((u >> 16) & 1u);
    return (unsigned short)(u >> 16);
}
__device__ inline float bf2f(unsigned short u) {
    return __uint_as_float(((unsigned int)u) << 16);
}

#define GLDS16(g, s)                                                            \
    __builtin_amdgcn_global_load_lds(                                           \
        (const __attribute__((address_space(1))) unsigned int*)(g),             \
        (__attribute__((address_space(3))) unsigned int*)(s), 16, 0, 0)

// ---------------- f32 -> bf16 convert ----------------
__global__ __launch_bounds__(256) void cvt_bf16(const float* __restrict__ in,
                                                unsigned short* __restrict__ out, int n) {
    int i = (blockIdx.x * 256 + threadIdx.x) * 4;
    if (i >= n) return;
    float4 v = *(const float4*)(in + i);
    u16x4 o;
    o[0] = f2bf(v.x); o[1] = f2bf(v.y); o[2] = f2bf(v.z); o[3] = f2bf(v.w);
    *(u16x4*)(out + i) = o;
}

// ---------------- RoPE/xPos tables ----------------
__global__ __launch_bounds__(256) void rope_tables(float* __restrict__ ct,
                                                   float* __restrict__ st,
                                                   float* __restrict__ sc) {
    int idx = blockIdx.x * 256 + threadIdx.x;
    if (idx >= kT * 32) return;
    int t = idx >> 5, i = idx & 31;
    float half = 2.0f * (float)i;
    float inv_freq = powf(10000.0f, -half / 64.0f);
    float fr = (float)t * inv_freq;
    float sv = (half + 0.4f * 64.0f) / (1.4f * 64.0f);
    float p = ((float)t - 1024.0f) / 512.0f;
    ct[idx] = cosf(fr);
    st[idx] = sinf(fr);
    sc[idx] = powf(sv, p);
}

// ---------------- fused qkv GEMM: C = xb @ wqkv^T (M4096, N3072, K1024) ---------
// tile 128x128, 4 waves. Epilogue: cols<2048 -> bf16 qkb[row][col];
// cols>=2048 -> V^T bf16 write vtb[(b*1024+col2)][t] (u16x4 = 4 consecutive t).
__global__ __launch_bounds__(256) void gemm_qkv(const unsigned short* __restrict__ A,
                                                const unsigned short* __restrict__ Bm,
                                                unsigned short* __restrict__ qkb,
                                                unsigned short* __restrict__ vtb) {
    constexpr int K = 1024;
    __shared__ __align__(16) unsigned short Al[128 * 64];
    __shared__ __align__(16) unsigned short Bl[128 * 64];
    char* ab = (char*)Al;
    char* bb = (char*)Bl;
    const int tid = threadIdx.x;
    const int l = tid & 63, w = tid >> 6;
    const int wr = w >> 1, wc = w & 1;
    const int tm = blockIdx.y * 128, tn = blockIdx.x * 128;
    const int ri = l >> 3;
    const int su = (l & 7) ^ (ri & 7);

    f32x4 zero4 = {0.0f, 0.0f, 0.0f, 0.0f};
    f32x4 acc[4][4];
#pragma unroll
    for (int m = 0; m < 4; m++)
#pragma unroll
        for (int n = 0; n < 4; n++) acc[m][n] = zero4;

    for (int kt = 0; kt < K; kt += 64) {
#pragma unroll
        for (int c = w; c < 32; c += 4) {
            if (c < 16) {
                const unsigned short* src = A + (size_t)(tm + c * 8 + ri) * K + kt + su * 8;
                GLDS16(src, ab + c * 1024);
            } else {
                int cb = c - 16;
                const unsigned short* src = Bm + (size_t)(tn + cb * 8 + ri) * K + kt + su * 8;
                GLDS16(src, bb + cb * 1024);
            }
        }
        __syncthreads();
#pragma unroll
        for (int ks = 0; ks < 2; ks++) {
            bf16x8 af[4], bfr[4];
            int kbyte = ks * 64 + (l >> 4) * 16;
#pragma unroll
            for (int m = 0; m < 4; m++) {
                int row = wr * 64 + m * 16 + (l & 15);
                af[m] = *(const bf16x8*)(ab + row * 128 + (kbyte ^ ((row & 7) << 4)));
            }
#pragma unroll
            for (int n = 0; n < 4; n++) {
                int row = wc * 64 + n * 16 + (l & 15);
                bfr[n] = *(const bf16x8*)(bb + row * 128 + (kbyte ^ ((row & 7) << 4)));
            }
#pragma unroll
            for (int m = 0; m < 4; m++)
#pragma unroll
                for (int n = 0; n < 4; n++)
                    acc[m][n] = __builtin_amdgcn_mfma_f32_16x16x32_bf16(af[m], bfr[n], acc[m][n], 0, 0, 0);
        }
        __syncthreads();
    }
    if (tn < 2048) {
#pragma unroll
        for (int m = 0; m < 4; m++)
#pragma unroll
            for (int n = 0; n < 4; n++)
#pragma unroll
                for (int r = 0; r < 4; r++) {
                    int row = tm + wr * 64 + m * 16 + (l >> 4) * 4 + r;
                    int col = tn + wc * 64 + n * 16 + (l & 15);
                    qkb[(size_t)row * 2048 + col] = f2bf(acc[m][n][r]);
                }
    } else {
#pragma unroll
        for (int m = 0; m < 4; m++)
#pragma unroll
            for (int n = 0; n < 4; n++) {
                int col2 = (tn - 2048) + wc * 64 + n * 16 + (l & 15);
                int rowb = tm + wr * 64 + m * 16 + (l >> 4) * 4;
                int b = rowb >> 11, t = rowb & 2047;
                u16x4 o;
#pragma unroll
                for (int r = 0; r < 4; r++) o[r] = f2bf(acc[m][n][r]);
                *(u16x4*)(vtb + ((size_t)(b * 1024 + col2)) * 2048 + t) = o;
            }
    }
}

// ---------------- RoPE q+k from bf16 qk; decay pre-scales for chunk=128 --------
__global__ __launch_bounds__(256) void rope_qk(const unsigned short* __restrict__ qkb,
                                               const float* __restrict__ ct,
                                               const float* __restrict__ st,
                                               const float* __restrict__ sc,
                                               unsigned short* __restrict__ dq,
                                               unsigned short* __restrict__ dk) {
    int idx = blockIdx.x * 256 + threadIdx.x;  // B*T*H*32
    if (idx >= kB * kT * kH * 32) return;
    int i = idx & 31;
    int h = (idx >> 5) & 15;
    int t = (idx >> 9) & 2047;
    int b = idx >> 20;
    const unsigned short* rowp = qkb + (size_t)(b * kT + t) * 2048 + h * kD + 2 * i;
    u16x2 qv2 = *(const u16x2*)(rowp);
    u16x2 kv2 = *(const u16x2*)(rowp + 1024);
    float qx = bf2f(qv2[0]), qy = bf2f(qv2[1]);
    float kx = bf2f(kv2[0]), ky = bf2f(kv2[1]);
    int ti = t * 32 + i;
    float c = ct[ti], s = st[ti], sv = sc[ti];
    float log2g = log2f(1.0f - exp2f(-5.0f - (float)h));
    float qdec = 0.125f * exp2f(log2g * (float)(t & 127));
    float kdec = exp2f(-log2g * (float)(t & 127));
    float cq = c * sv, sq = s * sv;
    float ck = c / sv, sk = s / sv;
    float q0 = (qx * cq - qy * sq) * qdec;
    float q1 = (qy * cq + qx * sq) * qdec;
    float k0 = (kx * ck - ky * sk) * kdec;
    float k1 = (ky * ck + kx * sk) * kdec;
    size_t doff = (((size_t)(b * kH + h) * kT + t) * kD) + 2 * i;
    u16x2 oq, ok;
    oq[0] = f2bf(q0); oq[1] = f2bf(q1);
    ok[0] = f2bf(k0); ok[1] = f2bf(k1);
    *(u16x2*)(dq + doff) = oq;
    *(u16x2*)(dk + doff) = ok;
}

// ---------------- K: bf16 (B,H,T,D) -> bf16 transposed (B,H,D,T) ----------------
__global__ __launch_bounds__(256) void kt_bf16(const unsigned short* __restrict__ kb,
                                               unsigned short* __restrict__ ktb) {
    __shared__ unsigned short tile[64][72];
    int tt = blockIdx.x * 64;
    int bh = blockIdx.y;
    int r = threadIdx.x >> 2;
    int cu = (threadIdx.x & 3) * 16;
    const unsigned short* srow = kb + ((size_t)bh * kT + tt + r) * kD + cu;
    bf16x8 i0 = *(const bf16x8*)(srow);
    bf16x8 i1 = *(const bf16x8*)(srow + 8);
#pragma unroll
    for (int e = 0; e < 8; e++) {
        tile[r][cu + e] = (unsigned short)i0[e];
        tile[r][cu + 8 + e] = (unsigned short)i1[e];
    }
    __syncthreads();
    int d = threadIdx.x >> 2;
    int tb = (threadIdx.x & 3) * 16;
    bf16x8 o0, o1;
#pragma unroll
    for (int e = 0; e < 8; e++) {
        o0[e] = (short)tile[tb + e][d];
        o1[e] = (short)tile[tb + 8 + e][d];
    }
    unsigned short* drow = ktb + ((size_t)bh * kD + d) * kT + tt + tb;
    *(bf16x8*)(drow) = o0;
    *(bf16x8*)(drow + 8) = o1;
}

// ---------------- chunk_m: Mt[bh][c] = g^128 * (V_c^T K~_c) as M^T[d2][d1], bf16 ----
// grid (32 bh, 16 c) -> XCD = bh%8.
__global__ __launch_bounds__(256) void chunk_m(const unsigned short* __restrict__ ktb,
                                               const unsigned short* __restrict__ vtb,
                                               unsigned short* __restrict__ Mt) {
    __shared__ __align__(16) unsigned short Ktl[64 * 128];
    __shared__ __align__(16) unsigned short Vtl[64 * 128];
    const int tid = threadIdx.x, l = tid & 63, w = tid >> 6;
    const int bh = blockIdx.x, c = blockIdx.y, h = bh & 15;
    const int ql = l & 31, hi5 = l >> 5;
    char* kp = (char*)Ktl;
    char* vp = (char*)Vtl;
#pragma unroll
    for (int j = 0; j < 4; ++j) {
        int ch = w * 4 + j;
        int row = ch * 4 + (l >> 4);
        int u = (l & 15) ^ (row & 15);
        GLDS16(ktb + ((size_t)bh * kD + row) * kT + c * 128 + u * 8, kp + ch * 1024);
        GLDS16(vtb + ((size_t)bh * kD + row) * kT + c * 128 + u * 8, vp + ch * 1024);
    }
    __syncthreads();
    const int iw = w >> 1, jw = w & 1;
    f32x16 acc;
#pragma unroll
    for (int r = 0; r < 16; ++r) acc[r] = 0.0f;
#pragma unroll
    for (int sk = 0; sk < 8; ++sk) {
        int rowa = iw * 32 + ql;
        int rowb = jw * 32 + ql;
        bf16x8 av = *(const bf16x8*)(vp + rowa * 256 + 16 * ((2 * sk + hi5) ^ (rowa & 15)));
        bf16x8 bk = *(const bf16x8*)(kp + rowb * 256 + 16 * ((2 * sk + hi5) ^ (rowb & 15)));
        acc = __builtin_amdgcn_mfma_f32_32x32x16_bf16(av, bk, acc, 0, 0, 0);
    }
    float log2g = log2f(1.0f - exp2f(-5.0f - (float)h));
    float gC = exp2f(128.0f * log2g);
    unsigned short* mo = Mt + ((size_t)(bh * kNC + c)) * 4096;
#pragma unroll
    for (int r = 0; r < 16; ++r) {
        int row = iw * 32 + (r & 3) + 8 * (r >> 2) + 4 * hi5;
        int col = jw * 32 + ql;
        mo[row * 64 + col] = f2bf(acc[r] * gC);
    }
}

// ---------------- chunk_states: St[bh][c] = sum_{j<c} gC^(c-1-j) Mt[bh][j], bf16 ----
__global__ __launch_bounds__(256) void chunk_states(const unsigned short* __restrict__ Mt,
                                                    unsigned short* __restrict__ St) {
    const int bh = blockIdx.x, c = blockIdx.y, h = bh & 15;
    const int tid = threadIdx.x;
    float log2g = log2f(1.0f - exp2f(-5.0f - (float)h));
    float gC = exp2f(128.0f * log2g);
    float acc[16];
#pragma unroll
    for (int e = 0; e < 16; ++e) acc[e] = 0.0f;
    for (int j = 0; j < c; ++j) {
        const unsigned short* m = Mt + ((size_t)(bh * kNC + j)) * 4096;
#pragma unroll
        for (int k = 0; k < 4; ++k) {
            u16x4 v = *(const u16x4*)(m + (k * 256 + tid) * 4);
#pragma unroll
            for (int e = 0; e < 4; ++e) {
                float f = bf2f(v[e]);
                acc[k * 4 + e] = acc[k * 4 + e] * gC + f;
            }
        }
    }
    unsigned short* so = St + ((size_t)(bh * kNC + c)) * 4096;
#pragma unroll
    for (int k = 0; k < 4; ++k) {
        u16x4 o;
#pragma unroll
        for (int e = 0; e < 4; ++e) o[e] = f2bf(acc[k * 4 + e]);
        *(u16x4*)(so + (k * 256 + tid) * 4) = o;
    }
}

// ---------------- chunk_attn: y_c = mask(Q~K~^T) V + Q~ S_c  (y bf16) ----------
// grid (32 bh, 16 c), 512 thr = 8 waves.
__global__ __launch_bounds__(512) void chunk_attn(const unsigned short* __restrict__ qb,
                                                  const unsigned short* __restrict__ kb,
                                                  const unsigned short* __restrict__ vtb,
                                                  const unsigned short* __restrict__ St,
                                                  unsigned short* __restrict__ yb) {
    __shared__ __align__(16) unsigned short Kt[128 * 64];
    __shared__ __align__(16) unsigned short Vt[64 * 128];
    __shared__ __align__(16) unsigned short Ss[64 * 64];
    __shared__ __align__(16) unsigned short Pl[8 * 32 * 64];
    const int tid = threadIdx.x, l = tid & 63, w = tid >> 6;
    const int bh = blockIdx.x, c = blockIdx.y;
    const int qw = w >> 1, dw = w & 1;
    const int ql = l & 31, hi5 = l >> 5;
    char* kp = (char*)Kt;
    char* vp = (char*)Vt;
    char* sp = (char*)Ss;
    char* pw = (char*)Pl + w * 4096;

#pragma unroll
    for (int j = 0; j < 2; ++j) {
        int ch = w * 2 + j;
        int row = ch * 8 + (l >> 3);
        int u = (l & 7) ^ (row & 7);
        GLDS16(kb + ((size_t)bh * kT + c * 128 + row) * kD + u * 8, kp + ch * 1024);
    }
#pragma unroll
    for (int j = 0; j < 2; ++j) {
        int ch = w * 2 + j;
        int row = ch * 4 + (l >> 4);
        int u = (l & 15) ^ (row & 15);
        GLDS16(vtb + ((size_t)bh * kD + row) * kT + c * 128 + u * 8, vp + ch * 1024);
    }
    {
        int row = w * 8 + (l >> 3);
        int u = (l & 7) ^ (row & 7);
        GLDS16(St + ((size_t)(bh * kNC + c)) * 4096 + row * 64 + u * 8, sp + w * 1024);
    }
    bf16x8 aq[4];
    {
        const unsigned short* qrow = qb + ((size_t)bh * kT + c * 128 + qw * 32 + ql) * kD + hi5 * 8;
#pragma unroll
        for (int dk = 0; dk < 4; ++dk) aq[dk] = *(const bf16x8*)(qrow + dk * 16);
    }
    __syncthreads();

    f32x16 acc;
#pragma unroll
    for (int r = 0; r < 16; ++r) acc[r] = 0.0f;
    const int qidx = qw * 32 + ql;

#pragma unroll
    for (int p = 0; p < 2; ++p) {
        f32x16 sA, sB;
#pragma unroll
        for (int r = 0; r < 16; ++r) { sA[r] = 0.0f; sB[r] = 0.0f; }
#pragma unroll
        for (int dk = 0; dk < 4; ++dk) {
            int rowa = (2 * p) * 32 + ql;
            int rowb = (2 * p + 1) * 32 + ql;
            bf16x8 ka = *(const bf16x8*)(kp + rowa * 128 + 16 * ((2 * dk + hi5) ^ (rowa & 7)));
            bf16x8 kb2 = *(const bf16x8*)(kp + rowb * 128 + 16 * ((2 * dk + hi5) ^ (rowb & 7)));
            sA = __builtin_amdgcn_mfma_f32_32x32x16_bf16(ka, aq[dk], sA, 0, 0, 0);
            sB = __builtin_amdgcn_mfma_f32_32x32x16_bf16(kb2, aq[dk], sB, 0, 0, 0);
        }
#pragma unroll
        for (int sb2 = 0; sb2 < 2; ++sb2) {
            int sbase = (2 * p + sb2) * 32 + 4 * hi5;
#pragma unroll
            for (int m = 0; m < 4; ++m) {
                float v0, v1, v2, v3;
                {
                    int s0i = sbase + 8 * m;
                    float x0 = sb2 ? sB[4 * m + 0] : sA[4 * m + 0];
                    float x1 = sb2 ? sB[4 * m + 1] : sA[4 * m + 1];
                    float x2 = sb2 ? sB[4 * m + 2] : sA[4 * m + 2];
                    float x3 = sb2 ? sB[4 * m + 3] : sA[4 * m + 3];
                    v0 = (qidx >= s0i + 0) ? x0 : 0.0f;
                    v1 = (qidx >= s0i + 1) ? x1 : 0.0f;
                    v2 = (qidx >= s0i + 2) ? x2 : 0.0f;
                    v3 = (qidx >= s0i + 3) ? x3 : 0.0f;
                }
                unsigned int lo, hi;
                asm("v_cvt_pk_bf16_f32 %0, %1, %2" : "=v"(lo) : "v"(v0), "v"(v1));
                asm("v_cvt_pk_bf16_f32 %0, %1, %2" : "=v"(hi) : "v"(v2), "v"(v3));
                u32x2 pr; pr[0] = lo; pr[1] = hi;
                *(u32x2*)(pw + ql * 128 + (((sb2 * 4 + m) * 16) ^ ((ql & 7) << 4)) + hi5 * 8) = pr;
            }
        }
#pragma unroll
        for (int kki = 0; kki < 4; ++kki) {
            bf16x8 ap = *(const bf16x8*)(pw + ql * 128 + 16 * ((2 * kki + hi5) ^ (ql & 7)));
            int rowv = dw * 32 + ql;
            bf16x8 bv = *(const bf16x8*)(vp + rowv * 256 + 16 * ((2 * (4 * p + kki) + hi5) ^ (rowv & 15)));
            acc = __builtin_amdgcn_mfma_f32_32x32x16_bf16(ap, bv, acc, 0, 0, 0);
        }
    }
#pragma unroll
    for (int dk = 0; dk < 4; ++dk) {
        int rows = dw * 32 + ql;
        bf16x8 bs = *(const bf16x8*)(sp + rows * 128 + 16 * ((2 * dk + hi5) ^ (rows & 7)));
        acc = __builtin_amdgcn_mfma_f32_32x32x16_bf16(aq[dk], bs, acc, 0, 0, 0);
    }
#pragma unroll
    for (int r = 0; r < 16; ++r) {
        int row = c * 128 + qw * 32 + (r & 3) + 8 * (r >> 2) + 4 * hi5;
        int col = dw * 32 + ql;
        yb[((size_t)bh * kT + row) * kD + col] = f2bf(acc[r]);
    }
}

// ---------------- GroupNorm stats (bf16 y): two-stage ----------------
__global__ __launch_bounds__(256) void gn_part(const unsigned short* __restrict__ yb,
                                               float* __restrict__ part) {
    int bh = blockIdx.y, seg = blockIdx.x;
    const unsigned short* p = yb + (size_t)bh * (kT * kD) + (size_t)seg * (kT * kD / 8);
    float s = 0.0f, s2 = 0.0f;
    for (int i = threadIdx.x; i < (kT * kD / 8) / 8; i += 256) {
        bf16x8 v = *(const bf16x8*)(p + i * 8);
#pragma unroll
        for (int e = 0; e < 8; ++e) {
            float f = bf2f((unsigned short)v[e]);
            s += f; s2 += f * f;
        }
    }
#pragma unroll
    for (int o = 32; o > 0; o >>= 1) {
        s += __shfl_down(s, o);
        s2 += __shfl_down(s2, o);
    }
    __shared__ float red[8];
    int tid = threadIdx.x;
    if ((tid & 63) == 0) {
        red[(tid >> 6) * 2] = s;
        red[(tid >> 6) * 2 + 1] = s2;
    }
    __syncthreads();
    if (tid == 0) {
        float S = 0.0f, S2 = 0.0f;
#pragma unroll
        for (int i = 0; i < 4; i++) { S += red[2 * i]; S2 += red[2 * i + 1]; }
        part[(bh * 8 + seg) * 2] = S;
        part[(bh * 8 + seg) * 2 + 1] = S2;
    }
}

__global__ __launch_bounds__(64) void gn_fin(const float* __restrict__ part,
                                             float* __restrict__ stats) {
    int bh = threadIdx.x;
    if (bh >= kB * kH) return;
    float S = 0.0f, S2 = 0.0f;
#pragma unroll
    for (int i = 0; i < 8; i++) {
        S += part[(bh * 8 + i) * 2];
        S2 += part[(bh * 8 + i) * 2 + 1];
    }
    const float inv = 1.0f / (float)(kT * kD);
    float mean = S * inv;
    float var = S2 * inv - mean * mean;
    stats[2 * bh] = mean;
    stats[2 * bh + 1] = rsqrtf(var + 1e-5f);
}

// ---------------- GEMM C[M,N] = A @ Bm^T; EPI 0 = fp32 store, 1 = silu bf16 -----
template <int TN, int EPI>
__global__ __launch_bounds__(256) void gemm_bt(const unsigned short* __restrict__ A,
                                               const unsigned short* __restrict__ Bm,
                                               float* __restrict__ Cf,
                                               unsigned short* __restrict__ Cb,
                                               int N, int K) {
    constexpr int NF = TN / 32;
    constexpr int CH = 16 + TN / 8;
    __shared__ __align__(16) unsigned short Al[128 * 64];
    __shared__ __align__(16) unsigned short Bl[TN * 64];
    char* ab = (char*)Al;
    char* bb = (char*)Bl;
    const int tid = threadIdx.x;
    const int l = tid & 63, w = tid >> 6;
    const int wr = w >> 1, wc = w & 1;
    const int tm = blockIdx.y * 128, tn = blockIdx.x * TN;
    const int ri = l >> 3;
    const int su = (l & 7) ^ (ri & 7);

    f32x4 zero4 = {0.0f, 0.0f, 0.0f, 0.0f};
    f32x4 acc[4][NF];
#pragma unroll
    for (int m = 0; m < 4; m++)
#pragma unroll
        for (int n = 0; n < NF; n++) acc[m][n] = zero4;

    for (int kt = 0; kt < K; kt += 64) {
#pragma unroll
        for (int c = w; c < CH; c += 4) {
            if (c < 16) {
                const unsigned short* src = A + (size_t)(tm + c * 8 + ri) * K + kt + su * 8;
                GLDS16(src, ab + c * 1024);
            } else {
                int cb = c - 16;
                const unsigned short* src = Bm + (size_t)(tn + cb * 8 + ri) * K + kt + su * 8;
                GLDS16(src, bb + cb * 1024);
            }
        }
        __syncthreads();
#pragma unroll
        for (int ks = 0; ks < 2; ks++) {
            bf16x8 af[4], bfr[NF];
            int kbyte = ks * 64 + (l >> 4) * 16;
#pragma unroll
            for (int m = 0; m < 4; m++) {
                int row = wr * 64 + m * 16 + (l & 15);
                af[m] = *(const bf16x8*)(ab + row * 128 + (kbyte ^ ((row & 7) << 4)));
            }
#pragma unroll
            for (int n = 0; n < NF; n++) {
                int row = wc * (TN / 2) + n * 16 + (l & 15);
                bfr[n] = *(const bf16x8*)(bb + row * 128 + (kbyte ^ ((row & 7) << 4)));
            }
#pragma unroll
            for (int m = 0; m < 4; m++)
#pragma unroll
                for (int n = 0; n < NF; n++)
                    acc[m][n] = __builtin_amdgcn_mfma_f32_16x16x32_bf16(af[m], bfr[n], acc[m][n], 0, 0, 0);
        }
        __syncthreads();
    }
#pragma unroll
    for (int m = 0; m < 4; m++)
#pragma unroll
        for (int n = 0; n < NF; n++)
#pragma unroll
            for (int r = 0; r < 4; r++) {
                int row = tm + wr * 64 + m * 16 + (l >> 4) * 4 + r;
                int col = tn + wc * (TN / 2) + n * 16 + (l & 15);
                float v = acc[m][n][r];
                if (EPI == 0) {
                    Cf[(size_t)row * N + col] = v;
                } else {
                    float sv = v / (1.0f + expf(-v));
                    Cb[(size_t)row * N + col] = f2bf(sv);
                }
            }
}

// ---------------- z = bf16( gsilu * ((y - mean)*rstd*gw + gb) ) ----------------
__global__ __launch_bounds__(256) void fuse_z(const unsigned short* __restrict__ gb,
                                              const unsigned short* __restrict__ yb,
                                              const float* __restrict__ stats,
                                              const float* __restrict__ gnw,
                                              const float* __restrict__ gnb,
                                              unsigned short* __restrict__ z) {
    int idx = blockIdx.x * 256 + threadIdx.x;  // (B*T*C)/4
    int row = idx >> 8;
    int c = (idx & 255) << 2;
    int b = row >> 11, t = row & 2047;
    int h = c >> 6, d = c & 63;
    int bh = b * kH + h;
    u16x4 gv = *(const u16x4*)(gb + (size_t)row * kC + c);
    u16x4 yv = *(const u16x4*)(yb + (((size_t)bh * kT) + t) * kD + d);
    float mean = stats[2 * bh], rstd = stats[2 * bh + 1];
    float4 wv = *(const float4*)(gnw + c);
    float4 bv = *(const float4*)(gnb + c);
    u16x4 o;
    o[0] = f2bf(bf2f(gv[0]) * ((bf2f(yv[0]) - mean) * rstd * wv.x + bv.x));
    o[1] = f2bf(bf2f(gv[1]) * ((bf2f(yv[1]) - mean) * rstd * wv.y + bv.y));
    o[2] = f2bf(bf2f(gv[2]) * ((bf2f(yv[2]) - mean) * rstd * wv.z + bv.z));
    o[3] = f2bf(bf2f(gv[3]) * ((bf2f(yv[3]) - mean) * rstd * wv.w + bv.w));
    *(u16x4*)(z + (size_t)row * kC + c) = o;
}

extern "C" void kernel_launch(void* const* d_in, const int* in_sizes, int n_in,
                              void* d_out, int out_size, void* d_ws, size_t ws_size,
                              hipStream_t stream) {
    const float* x = (const float*)d_in[0];
    const float* w_qkv = (const float*)d_in[1];
    const float* w_gated = (const float*)d_in[2];
    const float* w_proj = (const float*)d_in[3];
    const float* gnw = (const float*)d_in[4];
    const float* gnb = (const float*)d_in[5];
    float* out = (float*)d_out;
    char* ws = (char*)d_ws;

    unsigned short* xb      = (unsigned short*)(ws + 0);         // 8 MB
    unsigned short* wqkvb   = (unsigned short*)(ws + 8388608);   // 6 MB
    unsigned short* wgatedb = (unsigned short*)(ws + 14680064);  // 2 MB
    unsigned short* wprojb  = (unsigned short*)(ws + 16777216);  // 2 MB
    unsigned short* qb      = (unsigned short*)(ws + 18874368);  // 8 MB (B,H,T,D) pre-scaled
    unsigned short* kbuf    = (unsigned short*)(ws + 27262976);  // 8 MB (B,H,T,D) pre-scaled
    unsigned short* vtb     = (unsigned short*)(ws + 35651584);  // 8 MB (B,H,D,T)
    unsigned short* zb      = (unsigned short*)(ws + 44040192);  // 8 MB
    float* cosT  = (float*)(ws + 52428800);                      // 256 KB
    float* sinT  = (float*)(ws + 52690944);                      // 256 KB
    float* sclT  = (float*)(ws + 52953088);                      // 256 KB
    float* stats = (float*)(ws + 53215232);                      // 256 B
    unsigned short* qkb = (unsigned short*)(ws + 53215488);      // 16 MB bf16 qk GEMM out (dead after rope)
    unsigned short* ktb = (unsigned short*)(ws + 53215488);      // 8 MB (overlays qkb, after rope)
    unsigned short* Mt  = (unsigned short*)(ws + 61604096);      // 4 MB (overlays qkb)
    unsigned short* St  = (unsigned short*)(ws + 65798400);      // 4 MB (overlays qkb)
    unsigned short* yb  = (unsigned short*)(ws + 69992704);      // 8 MB bf16 y
    unsigned short* gbuf= (unsigned short*)(ws + 78381312);      // 8 MB bf16 silu(g)
    float* part  = (float*)(ws + 44040192);                      // gn partials (zb region)

    cvt_bf16<<<4096, 256, 0, stream>>>(x, xb, kB * kT * kC);
    cvt_bf16<<<3072, 256, 0, stream>>>(w_qkv, wqkvb, 3 * kC * kC);
    cvt_bf16<<<1024, 256, 0, stream>>>(w_gated, wgatedb, kC * kC);
    cvt_bf16<<<1024, 256, 0, stream>>>(w_proj, wprojb, kC * kC);
    rope_tables<<<256, 256, 0, stream>>>(cosT, sinT, sclT);

    // fused qkv GEMM: qk -> bf16 qkb, v -> V^T bf16 vtb directly
    gemm_qkv<<<dim3(3072 / 128, 4096 / 128), 256, 0, stream>>>(xb, wqkvb, qkb, vtb);
    rope_qk<<<8192, 256, 0, stream>>>(qkb, cosT, sinT, sclT, qb, kbuf);

    // k transpose -> (B,H,D,T)
    kt_bf16<<<dim3(kT / 64, kB * kH), 256, 0, stream>>>(kbuf, ktb);

    // chunked retention (bh fastest -> XCD = bh%8)
    chunk_m<<<dim3(kB * kH, kNC), 256, 0, stream>>>(ktb, vtb, Mt);
    chunk_states<<<dim3(kB * kH, kNC), 256, 0, stream>>>(Mt, St);
    chunk_attn<<<dim3(kB * kH, kNC), 512, 0, stream>>>(qb, kbuf, vtb, St, yb);

    gn_part<<<dim3(8, kB * kH), 256, 0, stream>>>(yb, part);
    gn_fin<<<1, 64, 0, stream>>>(part, stats);

    // gated branch: silu fused into GEMM epilogue (bf16 out)
    gemm_bt<64, 1><<<dim3(kC / 64, 4096 / 128), 256, 0, stream>>>(xb, wgatedb, nullptr, gbuf, kC, kC);
    fuse_z<<<4096, 256, 0, stream>>>(gbuf, yb, stats, gnw, gnb, zb);

    // proj -> out (fp32)
    gemm_bt<64, 0><<<dim3(kC / 64, 4096 / 128), 256, 0, stream>>>(zb, wprojb, out, nullptr, kC, kC);
}

// Round 7
// 143.283 us; speedup vs baseline: 1.2893x; 1.0275x over previous
//
#include <hip/hip_runtime.h>

typedef __attribute__((ext_vector_type(8))) short bf16x8;
typedef __attribute__((ext_vector_type(4))) float f32x4;
typedef __attribute__((ext_vector_type(16))) float f32x16;
typedef __attribute__((ext_vector_type(2))) unsigned short u16x2;
typedef __attribute__((ext_vector_type(4))) unsigned short u16x4;
typedef __attribute__((ext_vector_type(2))) unsigned int u32x2;

static constexpr int kB = 2;
static constexpr int kT = 2048;
static constexpr int kC = 1024;
static constexpr int kH = 16;
static constexpr int kD = 64;
static constexpr int kNC = 16;  // chunks of 128

__device__ inline unsigned short f2bf(float f) {
    unsigned int u = __float_as_uint(f);
    u += 0x7FFFu + ((u >> 16) & 1u);
    return (unsigned short)(u >> 16);
}
__device__ inline float bf2f(unsigned short u) {
    return __uint_as_float(((unsigned int)u) << 16);
}

#define GLDS16(g, s)                                                            \
    __builtin_amdgcn_global_load_lds(                                           \
        (const __attribute__((address_space(1))) unsigned int*)(g),             \
        (__attribute__((address_space(3))) unsigned int*)(s), 16, 0, 0)

// ---------------- f32 -> bf16 convert ----------------
__global__ __launch_bounds__(256) void cvt_bf16(const float* __restrict__ in,
                                                unsigned short* __restrict__ out, int n) {
    int i = (blockIdx.x * 256 + threadIdx.x) * 4;
    if (i >= n) return;
    float4 v = *(const float4*)(in + i);
    u16x4 o;
    o[0] = f2bf(v.x); o[1] = f2bf(v.y); o[2] = f2bf(v.z); o[3] = f2bf(v.w);
    *(u16x4*)(out + i) = o;
}

// ---------------- RoPE/xPos tables ----------------
__global__ __launch_bounds__(256) void rope_tables(float* __restrict__ ct,
                                                   float* __restrict__ st,
                                                   float* __restrict__ sc) {
    int idx = blockIdx.x * 256 + threadIdx.x;
    if (idx >= kT * 32) return;
    int t = idx >> 5, i = idx & 31;
    float half = 2.0f * (float)i;
    float inv_freq = powf(10000.0f, -half / 64.0f);
    float fr = (float)t * inv_freq;
    float sv = (half + 0.4f * 64.0f) / (1.4f * 64.0f);
    float p = ((float)t - 1024.0f) / 512.0f;
    ct[idx] = cosf(fr);
    st[idx] = sinf(fr);
    sc[idx] = powf(sv, p);
}

// ---------------- mega input GEMM: C = xb @ [wq;wk;wv;wg]^T (M4096,N4096,K1024) --
// tile 128x128, 4 waves, XCD-bijective swizzle (nwg=1024 % 8 == 0).
// Epilogue by col-block: q -> rope+decay -> qb; k -> rope+decay -> kbuf;
// v -> transposed bf16 vtb; gated -> silu bf16 gbuf.
__global__ __launch_bounds__(256) void gemm_qkvg(const unsigned short* __restrict__ A,
                                                 const unsigned short* __restrict__ Bm,
                                                 const float* __restrict__ ct,
                                                 const float* __restrict__ st,
                                                 const float* __restrict__ sc,
                                                 unsigned short* __restrict__ qb,
                                                 unsigned short* __restrict__ kbuf,
                                                 unsigned short* __restrict__ vtb,
                                                 unsigned short* __restrict__ gbuf) {
    constexpr int K = 1024;
    __shared__ __align__(16) unsigned short Al[128 * 64];
    __shared__ __align__(16) unsigned short Bl[128 * 64];
    char* ab = (char*)Al;
    char* bb = (char*)Bl;
    const int tid = threadIdx.x;
    const int l = tid & 63, w = tid >> 6;
    const int wr = w >> 1, wc = w & 1;
    // bijective XCD swizzle: xcd = id%8 owns 4 contiguous M-strips
    const int id = blockIdx.x;
    const int swz = (id & 7) * 128 + (id >> 3);
    const int by = swz >> 5, bx = swz & 31;
    const int tm = by * 128, tn = bx * 128;
    const int ri = l >> 3;
    const int su = (l & 7) ^ (ri & 7);

    f32x4 zero4 = {0.0f, 0.0f, 0.0f, 0.0f};
    f32x4 acc[4][4];
#pragma unroll
    for (int m = 0; m < 4; m++)
#pragma unroll
        for (int n = 0; n < 4; n++) acc[m][n] = zero4;

    for (int kt = 0; kt < K; kt += 64) {
#pragma unroll
        for (int c = w; c < 32; c += 4) {
            if (c < 16) {
                const unsigned short* src = A + (size_t)(tm + c * 8 + ri) * K + kt + su * 8;
                GLDS16(src, ab + c * 1024);
            } else {
                int cb = c - 16;
                const unsigned short* src = Bm + (size_t)(tn + cb * 8 + ri) * K + kt + su * 8;
                GLDS16(src, bb + cb * 1024);
            }
        }
        __syncthreads();
#pragma unroll
        for (int ks = 0; ks < 2; ks++) {
            bf16x8 af[4], bfr[4];
            int kbyte = ks * 64 + (l >> 4) * 16;
#pragma unroll
            for (int m = 0; m < 4; m++) {
                int row = wr * 64 + m * 16 + (l & 15);
                af[m] = *(const bf16x8*)(ab + row * 128 + (kbyte ^ ((row & 7) << 4)));
            }
#pragma unroll
            for (int n = 0; n < 4; n++) {
                int row = wc * 64 + n * 16 + (l & 15);
                bfr[n] = *(const bf16x8*)(bb + row * 128 + (kbyte ^ ((row & 7) << 4)));
            }
#pragma unroll
            for (int m = 0; m < 4; m++)
#pragma unroll
                for (int n = 0; n < 4; n++)
                    acc[m][n] = __builtin_amdgcn_mfma_f32_16x16x32_bf16(af[m], bfr[n], acc[m][n], 0, 0, 0);
        }
        __syncthreads();
    }

    if (tn < 2048) {
        // q or k: in-register RoPE + decay pre-scale, write (B,H,T,D) bf16
        const bool isq = (tn < 1024);
        unsigned short* dst = isq ? qb : kbuf;
#pragma unroll
        for (int n = 0; n < 4; n++) {
            int col = tn + wc * 64 + n * 16 + (l & 15);
            int h = (col >> 6) & 15;
            int d = col & 63;
            int i = d >> 1;
            float log2g = log2f(1.0f - exp2f(-5.0f - (float)h));
#pragma unroll
            for (int m = 0; m < 4; m++) {
#pragma unroll
                for (int r = 0; r < 4; r++) {
                    int row = tm + wr * 64 + m * 16 + (l >> 4) * 4 + r;
                    int b = row >> 11, t = row & 2047;
                    float x = acc[m][n][r];
                    float xp = __shfl_xor(x, 1);
                    int ti = t * 32 + i;
                    float cc = ct[ti], ss = st[ti], sv = sc[ti];
                    float cs, sn, dec;
                    if (isq) {
                        cs = cc * sv; sn = ss * sv;
                        dec = 0.125f * exp2f(log2g * (float)(t & 127));
                    } else {
                        cs = cc / sv; sn = ss / sv;
                        dec = exp2f(-log2g * (float)(t & 127));
                    }
                    float o = ((d & 1) ? (x * cs + xp * sn) : (x * cs - xp * sn)) * dec;
                    dst[((size_t)(b * 16 + h) * 2048 + t) * 64 + d] = f2bf(o);
                }
            }
        }
    } else if (tn < 3072) {
        // v: transposed bf16 write (B, Cv, T), u16x4 = 4 consecutive t
#pragma unroll
        for (int m = 0; m < 4; m++)
#pragma unroll
            for (int n = 0; n < 4; n++) {
                int col2 = (tn - 2048) + wc * 64 + n * 16 + (l & 15);
                int rowb = tm + wr * 64 + m * 16 + (l >> 4) * 4;
                int b = rowb >> 11, t = rowb & 2047;
                u16x4 o;
#pragma unroll
                for (int r = 0; r < 4; r++) o[r] = f2bf(acc[m][n][r]);
                *(u16x4*)(vtb + ((size_t)(b * 1024 + col2)) * 2048 + t) = o;
            }
    } else {
        // gated: silu -> bf16
#pragma unroll
        for (int m = 0; m < 4; m++)
#pragma unroll
            for (int n = 0; n < 4; n++)
#pragma unroll
                for (int r = 0; r < 4; r++) {
                    int row = tm + wr * 64 + m * 16 + (l >> 4) * 4 + r;
                    int col3 = (tn - 3072) + wc * 64 + n * 16 + (l & 15);
                    float v = acc[m][n][r];
                    float sv2 = v / (1.0f + expf(-v));
                    gbuf[(size_t)row * 1024 + col3] = f2bf(sv2);
                }
    }
}

// ---------------- K: bf16 (B,H,T,D) -> bf16 transposed (B,H,D,T) ----------------
__global__ __launch_bounds__(256) void kt_bf16(const unsigned short* __restrict__ kb,
                                               unsigned short* __restrict__ ktb) {
    __shared__ unsigned short tile[64][72];
    int tt = blockIdx.x * 64;
    int bh = blockIdx.y;
    int r = threadIdx.x >> 2;
    int cu = (threadIdx.x & 3) * 16;
    const unsigned short* srow = kb + ((size_t)bh * kT + tt + r) * kD + cu;
    bf16x8 i0 = *(const bf16x8*)(srow);
    bf16x8 i1 = *(const bf16x8*)(srow + 8);
#pragma unroll
    for (int e = 0; e < 8; e++) {
        tile[r][cu + e] = (unsigned short)i0[e];
        tile[r][cu + 8 + e] = (unsigned short)i1[e];
    }
    __syncthreads();
    int d = threadIdx.x >> 2;
    int tb = (threadIdx.x & 3) * 16;
    bf16x8 o0, o1;
#pragma unroll
    for (int e = 0; e < 8; e++) {
        o0[e] = (short)tile[tb + e][d];
        o1[e] = (short)tile[tb + 8 + e][d];
    }
    unsigned short* drow = ktb + ((size_t)bh * kD + d) * kT + tt + tb;
    *(bf16x8*)(drow) = o0;
    *(bf16x8*)(drow + 8) = o1;
}

// ---------------- chunk_m: Mt[bh][c] = g^128 * (V_c^T K~_c) as M^T[d2][d1], bf16 ----
__global__ __launch_bounds__(256) void chunk_m(const unsigned short* __restrict__ ktb,
                                               const unsigned short* __restrict__ vtb,
                                               unsigned short* __restrict__ Mt) {
    __shared__ __align__(16) unsigned short Ktl[64 * 128];
    __shared__ __align__(16) unsigned short Vtl[64 * 128];
    const int tid = threadIdx.x, l = tid & 63, w = tid >> 6;
    const int bh = blockIdx.x, c = blockIdx.y, h = bh & 15;
    const int ql = l & 31, hi5 = l >> 5;
    char* kp = (char*)Ktl;
    char* vp = (char*)Vtl;
#pragma unroll
    for (int j = 0; j < 4; ++j) {
        int ch = w * 4 + j;
        int row = ch * 4 + (l >> 4);
        int u = (l & 15) ^ (row & 15);
        GLDS16(ktb + ((size_t)bh * kD + row) * kT + c * 128 + u * 8, kp + ch * 1024);
        GLDS16(vtb + ((size_t)bh * kD + row) * kT + c * 128 + u * 8, vp + ch * 1024);
    }
    __syncthreads();
    const int iw = w >> 1, jw = w & 1;
    f32x16 acc;
#pragma unroll
    for (int r = 0; r < 16; ++r) acc[r] = 0.0f;
#pragma unroll
    for (int sk = 0; sk < 8; ++sk) {
        int rowa = iw * 32 + ql;
        int rowb = jw * 32 + ql;
        bf16x8 av = *(const bf16x8*)(vp + rowa * 256 + 16 * ((2 * sk + hi5) ^ (rowa & 15)));
        bf16x8 bk = *(const bf16x8*)(kp + rowb * 256 + 16 * ((2 * sk + hi5) ^ (rowb & 15)));
        acc = __builtin_amdgcn_mfma_f32_32x32x16_bf16(av, bk, acc, 0, 0, 0);
    }
    float log2g = log2f(1.0f - exp2f(-5.0f - (float)h));
    float gC = exp2f(128.0f * log2g);
    unsigned short* mo = Mt + ((size_t)(bh * kNC + c)) * 4096;
#pragma unroll
    for (int r = 0; r < 16; ++r) {
        int row = iw * 32 + (r & 3) + 8 * (r >> 2) + 4 * hi5;
        int col = jw * 32 + ql;
        mo[row * 64 + col] = f2bf(acc[r] * gC);
    }
}

// ---------------- chunk_states: St[bh][c] = sum_{j<c} gC^(c-1-j) Mt[bh][j], bf16 ----
__global__ __launch_bounds__(256) void chunk_states(const unsigned short* __restrict__ Mt,
                                                    unsigned short* __restrict__ St) {
    const int bh = blockIdx.x, c = blockIdx.y, h = bh & 15;
    const int tid = threadIdx.x;
    float log2g = log2f(1.0f - exp2f(-5.0f - (float)h));
    float gC = exp2f(128.0f * log2g);
    float acc[16];
#pragma unroll
    for (int e = 0; e < 16; ++e) acc[e] = 0.0f;
    for (int j = 0; j < c; ++j) {
        const unsigned short* m = Mt + ((size_t)(bh * kNC + j)) * 4096;
#pragma unroll
        for (int k = 0; k < 4; ++k) {
            u16x4 v = *(const u16x4*)(m + (k * 256 + tid) * 4);
#pragma unroll
            for (int e = 0; e < 4; ++e) {
                float f = bf2f(v[e]);
                acc[k * 4 + e] = acc[k * 4 + e] * gC + f;
            }
        }
    }
    unsigned short* so = St + ((size_t)(bh * kNC + c)) * 4096;
#pragma unroll
    for (int k = 0; k < 4; ++k) {
        u16x4 o;
#pragma unroll
        for (int e = 0; e < 4; ++e) o[e] = f2bf(acc[k * 4 + e]);
        *(u16x4*)(so + (k * 256 + tid) * 4) = o;
    }
}

// ---------------- chunk_attn: y_c = mask(Q~K~^T) V + Q~ S_c (y bf16) + GN partial --
__global__ __launch_bounds__(512) void chunk_attn(const unsigned short* __restrict__ qb,
                                                  const unsigned short* __restrict__ kb,
                                                  const unsigned short* __restrict__ vtb,
                                                  const unsigned short* __restrict__ St,
                                                  unsigned short* __restrict__ yb,
                                                  float* __restrict__ part) {
    __shared__ __align__(16) unsigned short Kt[128 * 64];
    __shared__ __align__(16) unsigned short Vt[64 * 128];
    __shared__ __align__(16) unsigned short Ss[64 * 64];
    __shared__ __align__(16) unsigned short Pl[8 * 32 * 64];
    __shared__ float red[16];
    const int tid = threadIdx.x, l = tid & 63, w = tid >> 6;
    const int bh = blockIdx.x, c = blockIdx.y;
    const int qw = w >> 1, dw = w & 1;
    const int ql = l & 31, hi5 = l >> 5;
    char* kp = (char*)Kt;
    char* vp = (char*)Vt;
    char* sp = (char*)Ss;
    char* pw = (char*)Pl + w * 4096;

#pragma unroll
    for (int j = 0; j < 2; ++j) {
        int ch = w * 2 + j;
        int row = ch * 8 + (l >> 3);
        int u = (l & 7) ^ (row & 7);
        GLDS16(kb + ((size_t)bh * kT + c * 128 + row) * kD + u * 8, kp + ch * 1024);
    }
#pragma unroll
    for (int j = 0; j < 2; ++j) {
        int ch = w * 2 + j;
        int row = ch * 4 + (l >> 4);
        int u = (l & 15) ^ (row & 15);
        GLDS16(vtb + ((size_t)bh * kD + row) * kT + c * 128 + u * 8, vp + ch * 1024);
    }
    {
        int row = w * 8 + (l >> 3);
        int u = (l & 7) ^ (row & 7);
        GLDS16(St + ((size_t)(bh * kNC + c)) * 4096 + row * 64 + u * 8, sp + w * 1024);
    }
    bf16x8 aq[4];
    {
        const unsigned short* qrow = qb + ((size_t)bh * kT + c * 128 + qw * 32 + ql) * kD + hi5 * 8;
#pragma unroll
        for (int dk = 0; dk < 4; ++dk) aq[dk] = *(const bf16x8*)(qrow + dk * 16);
    }
    __syncthreads();

    f32x16 acc;
#pragma unroll
    for (int r = 0; r < 16; ++r) acc[r] = 0.0f;
    const int qidx = qw * 32 + ql;

#pragma unroll
    for (int p = 0; p < 2; ++p) {
        f32x16 sA, sB;
#pragma unroll
        for (int r = 0; r < 16; ++r) { sA[r] = 0.0f; sB[r] = 0.0f; }
#pragma unroll
        for (int dk = 0; dk < 4; ++dk) {
            int rowa = (2 * p) * 32 + ql;
            int rowb = (2 * p + 1) * 32 + ql;
            bf16x8 ka = *(const bf16x8*)(kp + rowa * 128 + 16 * ((2 * dk + hi5) ^ (rowa & 7)));
            bf16x8 kb2 = *(const bf16x8*)(kp + rowb * 128 + 16 * ((2 * dk + hi5) ^ (rowb & 7)));
            sA = __builtin_amdgcn_mfma_f32_32x32x16_bf16(ka, aq[dk], sA, 0, 0, 0);
            sB = __builtin_amdgcn_mfma_f32_32x32x16_bf16(kb2, aq[dk], sB, 0, 0, 0);
        }
#pragma unroll
        for (int sb2 = 0; sb2 < 2; ++sb2) {
            int sbase = (2 * p + sb2) * 32 + 4 * hi5;
#pragma unroll
            for (int m = 0; m < 4; ++m) {
                float v0, v1, v2, v3;
                {
                    int s0i = sbase + 8 * m;
                    float x0 = sb2 ? sB[4 * m + 0] : sA[4 * m + 0];
                    float x1 = sb2 ? sB[4 * m + 1] : sA[4 * m + 1];
                    float x2 = sb2 ? sB[4 * m + 2] : sA[4 * m + 2];
                    float x3 = sb2 ? sB[4 * m + 3] : sA[4 * m + 3];
                    v0 = (qidx >= s0i + 0) ? x0 : 0.0f;
                    v1 = (qidx >= s0i + 1) ? x1 : 0.0f;
                    v2 = (qidx >= s0i + 2) ? x2 : 0.0f;
                    v3 = (qidx >= s0i + 3) ? x3 : 0.0f;
                }
                unsigned int lo, hi;
                asm("v_cvt_pk_bf16_f32 %0, %1, %2" : "=v"(lo) : "v"(v0), "v"(v1));
                asm("v_cvt_pk_bf16_f32 %0, %1, %2" : "=v"(hi) : "v"(v2), "v"(v3));
                u32x2 pr; pr[0] = lo; pr[1] = hi;
                *(u32x2*)(pw + ql * 128 + (((sb2 * 4 + m) * 16) ^ ((ql & 7) << 4)) + hi5 * 8) = pr;
            }
        }
#pragma unroll
        for (int kki = 0; kki < 4; ++kki) {
            bf16x8 ap = *(const bf16x8*)(pw + ql * 128 + 16 * ((2 * kki + hi5) ^ (ql & 7)));
            int rowv = dw * 32 + ql;
            bf16x8 bv = *(const bf16x8*)(vp + rowv * 256 + 16 * ((2 * (4 * p + kki) + hi5) ^ (rowv & 15)));
            acc = __builtin_amdgcn_mfma_f32_32x32x16_bf16(ap, bv, acc, 0, 0, 0);
        }
    }
#pragma unroll
    for (int dk = 0; dk < 4; ++dk) {
        int rows = dw * 32 + ql;
        bf16x8 bs = *(const bf16x8*)(sp + rows * 128 + 16 * ((2 * dk + hi5) ^ (rows & 7)));
        acc = __builtin_amdgcn_mfma_f32_32x32x16_bf16(aq[dk], bs, acc, 0, 0, 0);
    }
    // write y bf16 + accumulate GN partial from the rounded values
    float s = 0.0f, s2 = 0.0f;
#pragma unroll
    for (int r = 0; r < 16; ++r) {
        int row = c * 128 + qw * 32 + (r & 3) + 8 * (r >> 2) + 4 * hi5;
        int col = dw * 32 + ql;
        unsigned short ub = f2bf(acc[r]);
        yb[((size_t)bh * kT + row) * kD + col] = ub;
        float f = bf2f(ub);
        s += f; s2 += f * f;
    }
#pragma unroll
    for (int o = 32; o > 0; o >>= 1) {
        s += __shfl_down(s, o);
        s2 += __shfl_down(s2, o);
    }
    if (l == 0) { red[w * 2] = s; red[w * 2 + 1] = s2; }
    __syncthreads();
    if (tid == 0) {
        float S = 0.0f, S2 = 0.0f;
#pragma unroll
        for (int i = 0; i < 8; i++) { S += red[2 * i]; S2 += red[2 * i + 1]; }
        part[((size_t)bh * kNC + c) * 2] = S;
        part[((size_t)bh * kNC + c) * 2 + 1] = S2;
    }
}

__global__ __launch_bounds__(64) void gn_fin(const float* __restrict__ part,
                                             float* __restrict__ stats) {
    int bh = threadIdx.x;
    if (bh >= kB * kH) return;
    float S = 0.0f, S2 = 0.0f;
#pragma unroll
    for (int i = 0; i < kNC; i++) {
        S += part[(bh * kNC + i) * 2];
        S2 += part[(bh * kNC + i) * 2 + 1];
    }
    const float inv = 1.0f / (float)(kT * kD);
    float mean = S * inv;
    float var = S2 * inv - mean * mean;
    stats[2 * bh] = mean;
    stats[2 * bh + 1] = rsqrtf(var + 1e-5f);
}

// ---------------- GEMM C[M,N] = A @ Bm^T, fp32 out (proj) ----------------
__global__ __launch_bounds__(256) void gemm_proj(const unsigned short* __restrict__ A,
                                                 const unsigned short* __restrict__ Bm,
                                                 float* __restrict__ Cf,
                                                 int N, int K) {
    __shared__ __align__(16) unsigned short Al[128 * 64];
    __shared__ __align__(16) unsigned short Bl[128 * 64];
    char* ab = (char*)Al;
    char* bb = (char*)Bl;
    const int tid = threadIdx.x;
    const int l = tid & 63, w = tid >> 6;
    const int wr = w >> 1, wc = w & 1;
    const int tm = blockIdx.y * 128, tn = blockIdx.x * 128;
    const int ri = l >> 3;
    const int su = (l & 7) ^ (ri & 7);

    f32x4 zero4 = {0.0f, 0.0f, 0.0f, 0.0f};
    f32x4 acc[4][4];
#pragma unroll
    for (int m = 0; m < 4; m++)
#pragma unroll
        for (int n = 0; n < 4; n++) acc[m][n] = zero4;

    for (int kt = 0; kt < K; kt += 64) {
#pragma unroll
        for (int c = w; c < 32; c += 4) {
            if (c < 16) {
                const unsigned short* src = A + (size_t)(tm + c * 8 + ri) * K + kt + su * 8;
                GLDS16(src, ab + c * 1024);
            } else {
                int cb = c - 16;
                const unsigned short* src = Bm + (size_t)(tn + cb * 8 + ri) * K + kt + su * 8;
                GLDS16(src, bb + cb * 1024);
            }
        }
        __syncthreads();
#pragma unroll
        for (int ks = 0; ks < 2; ks++) {
            bf16x8 af[4], bfr[4];
            int kbyte = ks * 64 + (l >> 4) * 16;
#pragma unroll
            for (int m = 0; m < 4; m++) {
                int row = wr * 64 + m * 16 + (l & 15);
                af[m] = *(const bf16x8*)(ab + row * 128 + (kbyte ^ ((row & 7) << 4)));
            }
#pragma unroll
            for (int n = 0; n < 4; n++) {
                int row = wc * 64 + n * 16 + (l & 15);
                bfr[n] = *(const bf16x8*)(bb + row * 128 + (kbyte ^ ((row & 7) << 4)));
            }
#pragma unroll
            for (int m = 0; m < 4; m++)
#pragma unroll
                for (int n = 0; n < 4; n++)
                    acc[m][n] = __builtin_amdgcn_mfma_f32_16x16x32_bf16(af[m], bfr[n], acc[m][n], 0, 0, 0);
        }
        __syncthreads();
    }
#pragma unroll
    for (int m = 0; m < 4; m++)
#pragma unroll
        for (int n = 0; n < 4; n++)
#pragma unroll
            for (int r = 0; r < 4; r++) {
                int row = tm + wr * 64 + m * 16 + (l >> 4) * 4 + r;
                int col = tn + wc * 64 + n * 16 + (l & 15);
                Cf[(size_t)row * N + col] = acc[m][n][r];
            }
}

// ---------------- z = bf16( gsilu * ((y - mean)*rstd*gw + gb) ) ----------------
__global__ __launch_bounds__(256) void fuse_z(const unsigned short* __restrict__ gb,
                                              const unsigned short* __restrict__ yb,
                                              const float* __restrict__ stats,
                                              const float* __restrict__ gnw,
                                              const float* __restrict__ gnb,
                                              unsigned short* __restrict__ z) {
    int idx = blockIdx.x * 256 + threadIdx.x;  // (B*T*C)/4
    int row = idx >> 8;
    int c = (idx & 255) << 2;
    int b = row >> 11, t = row & 2047;
    int h = c >> 6, d = c & 63;
    int bh = b * kH + h;
    u16x4 gv = *(const u16x4*)(gb + (size_t)row * kC + c);
    u16x4 yv = *(const u16x4*)(yb + (((size_t)bh * kT) + t) * kD + d);
    float mean = stats[2 * bh], rstd = stats[2 * bh + 1];
    float4 wv = *(const float4*)(gnw + c);
    float4 bv = *(const float4*)(gnb + c);
    u16x4 o;
    o[0] = f2bf(bf2f(gv[0]) * ((bf2f(yv[0]) - mean) * rstd * wv.x + bv.x));
    o[1] = f2bf(bf2f(gv[1]) * ((bf2f(yv[1]) - mean) * rstd * wv.y + bv.y));
    o[2] = f2bf(bf2f(gv[2]) * ((bf2f(yv[2]) - mean) * rstd * wv.z + bv.z));
    o[3] = f2bf(bf2f(gv[3]) * ((bf2f(yv[3]) - mean) * rstd * wv.w + bv.w));
    *(u16x4*)(z + (size_t)row * kC + c) = o;
}

extern "C" void kernel_launch(void* const* d_in, const int* in_sizes, int n_in,
                              void* d_out, int out_size, void* d_ws, size_t ws_size,
                              hipStream_t stream) {
    const float* x = (const float*)d_in[0];
    const float* w_qkv = (const float*)d_in[1];
    const float* w_gated = (const float*)d_in[2];
    const float* w_proj = (const float*)d_in[3];
    const float* gnw = (const float*)d_in[4];
    const float* gnb = (const float*)d_in[5];
    float* out = (float*)d_out;
    char* ws = (char*)d_ws;

    unsigned short* xb      = (unsigned short*)(ws + 0);         // 8 MB
    unsigned short* wqkvb   = (unsigned short*)(ws + 8388608);   // 6 MB
    unsigned short* wgatedb = (unsigned short*)(ws + 14680064);  // 2 MB (contiguous after wqkvb)
    unsigned short* wprojb  = (unsigned short*)(ws + 16777216);  // 2 MB
    unsigned short* qb      = (unsigned short*)(ws + 18874368);  // 8 MB (B,H,T,D) rope+scaled
    unsigned short* kbuf    = (unsigned short*)(ws + 27262976);  // 8 MB (B,H,T,D) rope+scaled
    unsigned short* vtb     = (unsigned short*)(ws + 35651584);  // 8 MB (B,H,D,T)
    unsigned short* zb      = (unsigned short*)(ws + 44040192);  // 8 MB (part parked here early)
    float* cosT  = (float*)(ws + 52428800);                      // 256 KB
    float* sinT  = (float*)(ws + 52690944);                      // 256 KB
    float* sclT  = (float*)(ws + 52953088);                      // 256 KB
    float* stats = (float*)(ws + 53215232);                      // 256 B
    unsigned short* Mt  = (unsigned short*)(ws + 53215488);      // 4 MB
    unsigned short* St  = (unsigned short*)(ws + 57409792);      // 4 MB
    unsigned short* yb  = (unsigned short*)(ws + 61604096);      // 8 MB
    unsigned short* gbuf= (unsigned short*)(ws + 69992704);      // 8 MB
    unsigned short* ktb = (unsigned short*)(ws + 78381312);      // 8 MB -> ends 86769920
    float* part  = (float*)(ws + 44040192);                      // 4 KB in zb (dead before fuse_z)

    cvt_bf16<<<4096, 256, 0, stream>>>(x, xb, kB * kT * kC);
    cvt_bf16<<<3072, 256, 0, stream>>>(w_qkv, wqkvb, 3 * kC * kC);
    cvt_bf16<<<1024, 256, 0, stream>>>(w_gated, wgatedb, kC * kC);
    cvt_bf16<<<1024, 256, 0, stream>>>(w_proj, wprojb, kC * kC);
    rope_tables<<<256, 256, 0, stream>>>(cosT, sinT, sclT);

    // mega GEMM: q->qb (rope), k->kbuf (rope), v->vtb (transposed), gated->gbuf (silu)
    gemm_qkvg<<<1024, 256, 0, stream>>>(xb, wqkvb, cosT, sinT, sclT, qb, kbuf, vtb, gbuf);

    // k transpose -> (B,H,D,T)
    kt_bf16<<<dim3(kT / 64, kB * kH), 256, 0, stream>>>(kbuf, ktb);

    // chunked retention (bh fastest -> XCD = bh%8)
    chunk_m<<<dim3(kB * kH, kNC), 256, 0, stream>>>(ktb, vtb, Mt);
    chunk_states<<<dim3(kB * kH, kNC), 256, 0, stream>>>(Mt, St);
    chunk_attn<<<dim3(kB * kH, kNC), 512, 0, stream>>>(qb, kbuf, vtb, St, yb, part);

    gn_fin<<<1, 64, 0, stream>>>(part, stats);

    fuse_z<<<4096, 256, 0, stream>>>(gbuf, yb, stats, gnw, gnb, zb);

    // proj -> out (fp32)
    gemm_proj<<<dim3(kC / 128, 4096 / 128), 256, 0, stream>>>(zb, wprojb, out, kC, kC);
}